// Round 9
// baseline (1454.196 us; speedup 1.0000x reference)
//
#include <hip/hip_runtime.h>
#include <hip/hip_fp16.h>
#include <math.h>

#define N_NODES 50000
#define N_EDGES 1600000
#define NBUCK 196          // node >> 8 buckets (50000/256)
#define EBLK 400           // edge blocks for sort
#define CHUNK 4000         // edges per block (EBLK*CHUNK == N_EDGES)

typedef _Float16 f16x8 __attribute__((ext_vector_type(8)));
typedef _Float16 f16x4 __attribute__((ext_vector_type(4)));
typedef float f32x4 __attribute__((ext_vector_type(4)));

union HBits { __half h; unsigned short u; };

// ---------- dual bucket sort (dst-keyed for CSR, src-keyed for deg) ----------
__global__ __launch_bounds__(256) void k_bcount(const int* __restrict__ src,
                                                const int* __restrict__ dst,
                                                int* __restrict__ bcnt_d,
                                                int* __restrict__ bcnt_s) {
    __shared__ int lcd[256];
    __shared__ int lcs[256];
    int tid = threadIdx.x;
    lcd[tid] = 0; lcs[tid] = 0;
    __syncthreads();
    int base = blockIdx.x * CHUNK;
    for (int i = tid; i < CHUNK; i += 256) {
        atomicAdd(&lcd[dst[base + i] >> 8], 1);
        atomicAdd(&lcs[src[base + i] >> 8], 1);
    }
    __syncthreads();
    bcnt_d[blockIdx.x * 256 + tid] = lcd[tid];
    bcnt_s[blockIdx.x * 256 + tid] = lcs[tid];
}

// per-bucket scan over edge-blocks (parallel)
__global__ __launch_bounds__(256) void k_bscan1(int* __restrict__ bcnt_d,
                                                int* __restrict__ bcnt_s,
                                                int* __restrict__ btot) {
    int b = blockIdx.x & 255;
    int* bcnt = (blockIdx.x >> 8) ? bcnt_s : bcnt_d;
    int tid = threadIdx.x;
    int k0 = 2 * tid;
    int v0 = (k0 < EBLK) ? bcnt[k0 * 256 + b] : 0;
    int v1 = (k0 + 1 < EBLK) ? bcnt[(k0 + 1) * 256 + b] : 0;
    int pair = v0 + v1;
    __shared__ int s[256];
    s[tid] = pair;
    __syncthreads();
    for (int off = 1; off < 256; off <<= 1) {
        int t = (tid >= off) ? s[tid - off] : 0;
        __syncthreads();
        s[tid] += t;
        __syncthreads();
    }
    int excl = s[tid] - pair;
    if (k0 < EBLK)     bcnt[k0 * 256 + b] = excl;
    if (k0 + 1 < EBLK) bcnt[(k0 + 1) * 256 + b] = excl + v0;
    if (tid == 255) btot[(blockIdx.x >> 8) * 256 + b] = s[255];
}

__global__ __launch_bounds__(256) void k_bscan2(const int* __restrict__ btot,
                                                int* __restrict__ bstart_d,
                                                int* __restrict__ bstart_s,
                                                int* __restrict__ row_start) {
    __shared__ int s[256];
    int b = threadIdx.x;
    int v = btot[b];
    s[b] = v;
    __syncthreads();
    for (int off = 1; off < 256; off <<= 1) {
        int t = (b >= off) ? s[b - off] : 0;
        __syncthreads();
        s[b] += t;
        __syncthreads();
    }
    bstart_d[b] = s[b] - v;
    if (b == 0) {
        bstart_d[256] = N_EDGES;
        row_start[N_NODES] = N_EDGES;
    }
    __syncthreads();
    int v2 = btot[256 + b];
    s[b] = v2;
    __syncthreads();
    for (int off = 1; off < 256; off <<= 1) {
        int t = (b >= off) ? s[b - off] : 0;
        __syncthreads();
        s[b] += t;
        __syncthreads();
    }
    bstart_s[b] = s[b] - v2;
    if (b == 0) bstart_s[256] = N_EDGES;
}

// scatter packed records into both sorted orders (LDS cursors only)
__global__ __launch_bounds__(256) void k_bscatter(const int* __restrict__ src,
                                                  const int* __restrict__ dst,
                                                  const float* __restrict__ w,
                                                  const int* __restrict__ bcnt_d,
                                                  const int* __restrict__ bcnt_s,
                                                  const int* __restrict__ bstart_d,
                                                  const int* __restrict__ bstart_s,
                                                  uint2* __restrict__ dsw,
                                                  uint2* __restrict__ ssw) {
    __shared__ int curd[256];
    __shared__ int curs[256];
    int tid = threadIdx.x;
    curd[tid] = bcnt_d[blockIdx.x * 256 + tid] + bstart_d[tid];
    curs[tid] = bcnt_s[blockIdx.x * 256 + tid] + bstart_s[tid];
    __syncthreads();
    int base = blockIdx.x * CHUNK;
    for (int i = tid; i < CHUNK; i += 256) {
        int d = dst[base + i];
        int ss = src[base + i];
        float wi = w[base + i];
        unsigned wb = __float_as_uint(wi);
        int p = atomicAdd(&curd[d >> 8], 1);   // LDS atomic
        uint2 r; r.x = (unsigned)ss | ((unsigned)(d & 255) << 16); r.y = wb;
        dsw[p] = r;
        int q = atomicAdd(&curs[ss >> 8], 1);  // LDS atomic
        uint2 r2; r2.x = (unsigned)(ss & 255); r2.y = wb;
        ssw[q] = r2;
    }
}

// deg per src-bucket -> dinv
__global__ __launch_bounds__(256) void k_sdeg(const uint2* __restrict__ ssw,
                                              const int* __restrict__ bstart_s,
                                              float* __restrict__ dinv) {
    __shared__ float h[256];
    int tid = threadIdx.x;
    int b = blockIdx.x;
    h[tid] = 0.f;
    __syncthreads();
    int e0 = bstart_s[b], e1 = bstart_s[b + 1];
    for (int i = e0 + tid; i < e1; i += 256) {
        uint2 r = ssw[i];
        atomicAdd(&h[r.x & 255], __uint_as_float(r.y));  // LDS atomic
    }
    __syncthreads();
    int node = (b << 8) + tid;
    if (node < N_NODES) {
        float d = h[tid];
        dinv[node] = d > 0.f ? rsqrtf(fmaxf(d, 1e-30f)) : 0.f;
    }
}

// per-bucket CSR build + inline norm; csr entry = src(16b) | f16norm << 16
__global__ __launch_bounds__(256) void k_bcsr(const uint2* __restrict__ dsw,
                                              const int* __restrict__ bstart_d,
                                              const float* __restrict__ dinv,
                                              int* __restrict__ row_start,
                                              unsigned* __restrict__ csr4) {
    __shared__ int ncnt[256];
    __shared__ int cur[256];
    __shared__ int sc[256];
    __shared__ float ldinv[256];
    int tid = threadIdx.x;
    int b = blockIdx.x;
    int node = (b << 8) + tid;
    ncnt[tid] = 0;
    ldinv[tid] = (node < N_NODES) ? dinv[node] : 0.f;
    __syncthreads();
    int e0 = bstart_d[b], e1 = bstart_d[b + 1];
    for (int i = e0 + tid; i < e1; i += 256)
        atomicAdd(&ncnt[(dsw[i].x >> 16) & 255], 1);  // LDS atomic
    __syncthreads();
    int v = ncnt[tid];
    sc[tid] = v;
    __syncthreads();
    for (int off = 1; off < 256; off <<= 1) {
        int t = (tid >= off) ? sc[tid - off] : 0;
        __syncthreads();
        sc[tid] += t;
        __syncthreads();
    }
    int excl = sc[tid] - v;
    cur[tid] = excl;
    if (node < N_NODES) row_start[node] = e0 + excl;
    __syncthreads();
    for (int i = e0 + tid; i < e1; i += 256) {
        uint2 sw = dsw[i];
        int srcn = sw.x & 0xFFFF;
        int ld = (sw.x >> 16) & 255;
        int p = e0 + atomicAdd(&cur[ld], 1);  // LDS atomic
        float nv = -dinv[srcn] * __uint_as_float(sw.y) * ldinv[ld];
        HBits hb; hb.h = __float2half(nv);
        csr4[p] = (unsigned)srcn | ((unsigned)hb.u << 16);
    }
}

// x fp32 -> X f16 (N x 128 contiguous)
__global__ void k_cvt_x(const float* __restrict__ x, __half* __restrict__ X, int n4) {
    int i = blockIdx.x * blockDim.x + threadIdx.x;
    if (i < n4) {
        float4 v = *(const float4*)&x[(size_t)i * 4];
        f16x4 o;
        o[0] = (_Float16)v.x; o[1] = (_Float16)v.y;
        o[2] = (_Float16)v.z; o[3] = (_Float16)v.w;
        *(f16x4*)&X[(size_t)i * 4] = o;
    }
}

// Build combined transposed weights for one layer:
// Wt[n*128 + k], n in [0,3C): slice0 = 2*W2, slice1 = W1, slice2 = W0 - W2.
__global__ void k_wt(const float* __restrict__ W, __half* __restrict__ Wt, int C) {
    int i = blockIdx.x * blockDim.x + threadIdx.x;
    if (i < 3 * C * 128) {
        int n = i >> 7, k = i & 127;
        int slice = n / C, c = n % C;
        float v;
        if (slice == 0)      v = 2.f * W[(size_t)(256 + k) * C + c];
        else if (slice == 1) v = W[(size_t)(128 + k) * C + c];
        else                 v = W[(size_t)k * C + c] - W[(size_t)(256 + k) * C + c];
        Wt[i] = __float2half(v);
    }
}

// ---------- SpMM: XCD-sliced features, one wave per (node, slice) ----------
// blockIdx.x & 7 = feature slice -> lands on a fixed XCD (round-robin
// dispatch): per-XCD gather working set = N_NODES*SFEAT*2B (1.6MB/0.8MB)
// fits the 4MB per-XCD L2 (R7 profile: 154MB FETCH dominated by 8x per-XCD
// replication of the full 12.8MB slice). Strides are template constants
// (R7's runtime strides caused a VALU address-math bloat: 39->70% VALUBusy).
template <int ST_IN, int ST_ADD, int ST_OUT, int NFT, int SIG, int F32>
__global__ __launch_bounds__(256) void k_spmm(const __half* __restrict__ Xin,
                                              const __half* __restrict__ Add,
                                              void* __restrict__ outp,
                                              const float* __restrict__ bias,
                                              const int* __restrict__ row_start,
                                              const unsigned* __restrict__ csr4) {
    constexpr int SFEAT = NFT / 8;      // feats per slice (16 or 8)
    constexpr int NL = SFEAT / 8;       // feature lanes per edge (2 or 1)
    constexpr int EGN = 64 / NL;        // edges per iter (32 or 64)
    int fslice = blockIdx.x & 7;
    int nb = blockIdx.x >> 3;
    int node = nb * 4 + (threadIdx.x >> 6);
    int lane = threadIdx.x & 63;
    int eg = lane / NL;
    int fs = lane % NL;
    int s = row_start[node];
    int e = row_start[node + 1];
    const __half* Tbase = Xin + fslice * SFEAT + fs * 8;
    float acc[8];
    #pragma unroll
    for (int f = 0; f < 8; f++) acc[f] = 0.f;

    int j = s;
    for (; j + EGN <= e; j += EGN) {
        unsigned mye = csr4[j + (lane & (EGN - 1))];
        unsigned ent = (NL == 1) ? mye : (unsigned)__shfl((int)mye, eg);
        int sp = (int)(ent & 0xFFFFu);
        HBits hb; hb.u = (unsigned short)(ent >> 16);
        float nv = __half2float(hb.h);
        f16x8 r = *(const f16x8*)&Tbase[(size_t)sp * ST_IN];
        #pragma unroll
        for (int f = 0; f < 8; f++) acc[f] = fmaf(nv, (float)r[f], acc[f]);
    }
    int rem = e - j;
    if (rem > 0) {
        unsigned mye = csr4[j + min(lane & (EGN - 1), rem - 1)];
        unsigned ent;
        if (NL == 1) ent = mye;
        else {
            int sli = (eg < rem) ? eg : 0;
            ent = (unsigned)__shfl((int)mye, sli);
        }
        int sp = (int)(ent & 0xFFFFu);
        HBits hb; hb.u = (unsigned short)(ent >> 16);
        float nv = (eg < rem) ? __half2float(hb.h) : 0.f;
        f16x8 r = *(const f16x8*)&Tbase[(size_t)sp * ST_IN];
        #pragma unroll
        for (int f = 0; f < 8; f++) acc[f] = fmaf(nv, (float)r[f], acc[f]);
    }
    // reduce edge-group partials (over lane bits above the fs bits)
    #pragma unroll
    for (int f = 0; f < 8; f++)
        for (int m = NL; m < 64; m <<= 1)
            acc[f] += __shfl_xor(acc[f], m);
    if (eg == 0) {
        int fb = fslice * SFEAT + fs * 8;
        f16x8 av = *(const f16x8*)&Add[(size_t)node * ST_ADD + fb];
        float v[8];
        #pragma unroll
        for (int f = 0; f < 8; f++) v[f] = acc[f] + (float)av[f];
        if (SIG) {
            #pragma unroll
            for (int f = 0; f < 8; f++) {
                v[f] += bias[fb + f];
                v[f] = 1.f / (1.f + expf(-v[f]));
            }
        }
        if (F32) {
            float* o = (float*)outp + (size_t)node * ST_OUT + fb;
            float4 o0; o0.x = v[0]; o0.y = v[1]; o0.z = v[2]; o0.w = v[3];
            float4 o1; o1.x = v[4]; o1.y = v[5]; o1.z = v[6]; o1.w = v[7];
            *(float4*)&o[0] = o0;
            *(float4*)&o[4] = o1;
        } else {
            f16x8 o;
            #pragma unroll
            for (int f = 0; f < 8; f++) o[f] = (_Float16)v[f];
            *(f16x8*)((__half*)outp + (size_t)node * ST_OUT + fb) = o;
        }
    }
}

// ---------- MFMA GEMM: G[M x 3C] = X[M x 128] @ Wt^T, col-chunk CC per block.y
// mfma_f32_16x16x32_f16: A[m=lane&15][k=(lane>>4)*8+j]; C/D col=lane&15,row=(lane>>4)*4+r.
template <int CC>
__global__ __launch_bounds__(256) void k_gemm(const __half* __restrict__ A,
                                              const __half* __restrict__ Wt,
                                              __half* __restrict__ G, int M) {
    constexpr int NF = CC / 16;
    constexpr int N3 = 3 * CC;
    __shared__ _Float16 As[64][56];
    __shared__ _Float16 Bs[CC][56];
    int tid = threadIdx.x;
    int wave = tid >> 6, lane = tid & 63;
    int lm = lane & 15, lq = lane >> 4;
    int m0 = blockIdx.x * 64;
    int n0 = blockIdx.y * CC;
    f32x4 acc[NF];
    for (int nf = 0; nf < NF; nf++) acc[nf] = (f32x4)0.0f;

    for (int k0 = 0; k0 < 128; k0 += 32) {
        {
            int r = tid >> 2, q = tid & 3;
            int row = m0 + r;
            if (row >= M) row = M - 1;
            *(f16x8*)&As[r][q * 8] = *(const f16x8*)&A[(size_t)row * 128 + k0 + q * 8];
        }
        for (int i = 0; i < CC / 64; i++) {
            int idx = tid + i * 256;
            int n = idx >> 2, q = idx & 3;
            *(f16x8*)&Bs[n][q * 8] = *(const f16x8*)&Wt[(size_t)(n0 + n) * 128 + k0 + q * 8];
        }
        __syncthreads();
        f16x8 a = *(const f16x8*)&As[wave * 16 + lm][lq * 8];
        for (int nf = 0; nf < NF; nf++) {
            f16x8 b = *(const f16x8*)&Bs[nf * 16 + lm][lq * 8];
            acc[nf] = __builtin_amdgcn_mfma_f32_16x16x32_f16(a, b, acc[nf], 0, 0, 0);
        }
        __syncthreads();
    }
    for (int nf = 0; nf < NF; nf++) {
        for (int r = 0; r < 4; r++) {
            int grow = m0 + wave * 16 + lq * 4 + r;
            int col = n0 + nf * 16 + lm;
            if (grow < M)
                G[(size_t)grow * N3 + col] = __float2half(acc[nf][r]);
        }
    }
}

extern "C" void kernel_launch(void* const* d_in, const int* in_sizes, int n_in,
                              void* d_out, int out_size, void* d_ws, size_t ws_size,
                              hipStream_t stream) {
    const float* x  = (const float*)d_in[0];
    const int*   ei = (const int*)d_in[1];
    const float* ew = (const float*)d_in[2];
    const float* W0 = (const float*)d_in[3];
    const float* b0 = (const float*)d_in[4];
    const float* W1 = (const float*)d_in[5];
    const float* b1 = (const float*)d_in[6];
    const float* W2 = (const float*)d_in[7];
    const float* b2 = (const float*)d_in[8];
    const int* src = ei;
    const int* dst = ei + N_EDGES;

    char* ws = (char*)d_ws;
    size_t off = 0;
    auto alloc = [&](size_t bytes) -> char* {
        size_t p = (off + 255) & ~(size_t)255;
        off = p + bytes;
        return ws + p;
    };
    __half*   X      = (__half*)alloc((size_t)N_NODES * 128 * 2);
    __half*   G      = (__half*)alloc((size_t)N_NODES * 384 * 2);   // [P|Q|S] per layer
    __half*   TMP    = (__half*)alloc((size_t)N_NODES * 128 * 2);   // L*P + Q
    unsigned* csr4   = (unsigned*)alloc((size_t)N_EDGES * 4);       // src | f16norm<<16
    uint2*    dsw    = (uint2*)alloc((size_t)N_EDGES * 8);
    uint2*    ssw    = (uint2*)alloc((size_t)N_EDGES * 8);
    int*      bcnt_d = (int*)alloc((size_t)EBLK * 256 * 4);
    int*      bcnt_s = (int*)alloc((size_t)EBLK * 256 * 4);
    int*      btot   = (int*)alloc(512 * 4);
    int*      bstart_d = (int*)alloc(257 * 4);
    int*      bstart_s = (int*)alloc(257 * 4);
    int*      row_start= (int*)alloc((size_t)(N_NODES + 1) * 4);
    float*    dinv   = (float*)alloc((size_t)N_NODES * 4);
    __half*   Wt0    = (__half*)alloc((size_t)384 * 128 * 2);
    __half*   Wt1    = (__half*)alloc((size_t)384 * 128 * 2);
    __half*   Wt2    = (__half*)alloc((size_t)192 * 128 * 2);

    // dual bucket sort; zero device-scope atomics anywhere
    k_bcount<<<EBLK, 256, 0, stream>>>(src, dst, bcnt_d, bcnt_s);
    k_bscan1<<<512, 256, 0, stream>>>(bcnt_d, bcnt_s, btot);
    k_bscan2<<<1, 256, 0, stream>>>(btot, bstart_d, bstart_s, row_start);
    k_bscatter<<<EBLK, 256, 0, stream>>>(src, dst, ew, bcnt_d, bcnt_s,
                                         bstart_d, bstart_s, dsw, ssw);
    k_sdeg<<<NBUCK, 256, 0, stream>>>(ssw, bstart_s, dinv);
    k_bcsr<<<NBUCK, 256, 0, stream>>>(dsw, bstart_d, dinv, row_start, csr4);

    k_cvt_x<<<(N_NODES * 32 + 255) / 256, 256, 0, stream>>>(x, X, N_NODES * 32);
    k_wt<<<(3 * 128 * 128 + 255) / 256, 256, 0, stream>>>(W0, Wt0, 128);
    k_wt<<<(3 * 128 * 128 + 255) / 256, 256, 0, stream>>>(W1, Wt1, 128);
    k_wt<<<(3 * 64 * 128 + 255) / 256, 256, 0, stream>>>(W2, Wt2, 64);

    int gb = (N_NODES + 63) / 64;        // 782
    int sb = (N_NODES / 4) * 8;          // 100000 (node-blocks x 8 XCD slices)
    // layer 0: G = X @ [Wc|Wb|Wa];  TMP = L*P + Q;  X = sigmoid(L*TMP + S + b0)
    k_gemm<128><<<dim3(gb, 3), 256, 0, stream>>>(X, Wt0, G, N_NODES);
    k_spmm<384, 384, 128, 128, 0, 0><<<sb, 256, 0, stream>>>(G, G + 128, TMP,
                                                             nullptr, row_start, csr4);
    k_spmm<128, 384, 128, 128, 1, 0><<<sb, 256, 0, stream>>>(TMP, G + 256, X,
                                                             b0, row_start, csr4);
    // layer 1
    k_gemm<128><<<dim3(gb, 3), 256, 0, stream>>>(X, Wt1, G, N_NODES);
    k_spmm<384, 384, 128, 128, 0, 0><<<sb, 256, 0, stream>>>(G, G + 128, TMP,
                                                             nullptr, row_start, csr4);
    k_spmm<128, 384, 128, 128, 1, 0><<<sb, 256, 0, stream>>>(TMP, G + 256, X,
                                                             b1, row_start, csr4);
    // layer 2 (C=64): G = N x 192
    k_gemm<64><<<dim3(gb, 3), 256, 0, stream>>>(X, Wt2, G, N_NODES);
    k_spmm<192, 192, 64, 64, 0, 0><<<sb, 256, 0, stream>>>(G, G + 64, TMP,
                                                           nullptr, row_start, csr4);
    k_spmm<64, 192, 64, 64, 1, 1><<<sb, 256, 0, stream>>>(TMP, G + 128, d_out,
                                                          b2, row_start, csr4);
}

// Round 10
// 523.507 us; speedup vs baseline: 2.7778x; 2.7778x over previous
//
#include <hip/hip_runtime.h>
#include <hip/hip_fp16.h>
#include <math.h>

#define N_NODES 50000
#define N_EDGES 1600000
#define NBUCK 196          // node >> 8 buckets (50000/256)
#define EBLK 400           // edge blocks for sort
#define CHUNK 4000         // edges per block (EBLK*CHUNK == N_EDGES)

typedef _Float16 f16x8 __attribute__((ext_vector_type(8)));
typedef _Float16 f16x4 __attribute__((ext_vector_type(4)));
typedef float f32x4 __attribute__((ext_vector_type(4)));

union HBits { __half h; unsigned short u; };

// ---------- dual bucket sort (dst-keyed for CSR, src-keyed for deg) ----------
__global__ __launch_bounds__(256) void k_bcount(const int* __restrict__ src,
                                                const int* __restrict__ dst,
                                                int* __restrict__ bcnt_d,
                                                int* __restrict__ bcnt_s) {
    __shared__ int lcd[256];
    __shared__ int lcs[256];
    int tid = threadIdx.x;
    lcd[tid] = 0; lcs[tid] = 0;
    __syncthreads();
    int base = blockIdx.x * CHUNK;
    for (int i = tid; i < CHUNK; i += 256) {
        atomicAdd(&lcd[dst[base + i] >> 8], 1);
        atomicAdd(&lcs[src[base + i] >> 8], 1);
    }
    __syncthreads();
    bcnt_d[blockIdx.x * 256 + tid] = lcd[tid];
    bcnt_s[blockIdx.x * 256 + tid] = lcs[tid];
}

// per-bucket scan over edge-blocks (parallel)
__global__ __launch_bounds__(256) void k_bscan1(int* __restrict__ bcnt_d,
                                                int* __restrict__ bcnt_s,
                                                int* __restrict__ btot) {
    int b = blockIdx.x & 255;
    int* bcnt = (blockIdx.x >> 8) ? bcnt_s : bcnt_d;
    int tid = threadIdx.x;
    int k0 = 2 * tid;
    int v0 = (k0 < EBLK) ? bcnt[k0 * 256 + b] : 0;
    int v1 = (k0 + 1 < EBLK) ? bcnt[(k0 + 1) * 256 + b] : 0;
    int pair = v0 + v1;
    __shared__ int s[256];
    s[tid] = pair;
    __syncthreads();
    for (int off = 1; off < 256; off <<= 1) {
        int t = (tid >= off) ? s[tid - off] : 0;
        __syncthreads();
        s[tid] += t;
        __syncthreads();
    }
    int excl = s[tid] - pair;
    if (k0 < EBLK)     bcnt[k0 * 256 + b] = excl;
    if (k0 + 1 < EBLK) bcnt[(k0 + 1) * 256 + b] = excl + v0;
    if (tid == 255) btot[(blockIdx.x >> 8) * 256 + b] = s[255];
}

__global__ __launch_bounds__(256) void k_bscan2(const int* __restrict__ btot,
                                                int* __restrict__ bstart_d,
                                                int* __restrict__ bstart_s,
                                                int* __restrict__ row_start) {
    __shared__ int s[256];
    int b = threadIdx.x;
    int v = btot[b];
    s[b] = v;
    __syncthreads();
    for (int off = 1; off < 256; off <<= 1) {
        int t = (b >= off) ? s[b - off] : 0;
        __syncthreads();
        s[b] += t;
        __syncthreads();
    }
    bstart_d[b] = s[b] - v;
    if (b == 0) {
        bstart_d[256] = N_EDGES;
        row_start[N_NODES] = N_EDGES;
    }
    __syncthreads();
    int v2 = btot[256 + b];
    s[b] = v2;
    __syncthreads();
    for (int off = 1; off < 256; off <<= 1) {
        int t = (b >= off) ? s[b - off] : 0;
        __syncthreads();
        s[b] += t;
        __syncthreads();
    }
    bstart_s[b] = s[b] - v2;
    if (b == 0) bstart_s[256] = N_EDGES;
}

// scatter packed records into both sorted orders (LDS cursors only)
__global__ __launch_bounds__(256) void k_bscatter(const int* __restrict__ src,
                                                  const int* __restrict__ dst,
                                                  const float* __restrict__ w,
                                                  const int* __restrict__ bcnt_d,
                                                  const int* __restrict__ bcnt_s,
                                                  const int* __restrict__ bstart_d,
                                                  const int* __restrict__ bstart_s,
                                                  uint2* __restrict__ dsw,
                                                  uint2* __restrict__ ssw) {
    __shared__ int curd[256];
    __shared__ int curs[256];
    int tid = threadIdx.x;
    curd[tid] = bcnt_d[blockIdx.x * 256 + tid] + bstart_d[tid];
    curs[tid] = bcnt_s[blockIdx.x * 256 + tid] + bstart_s[tid];
    __syncthreads();
    int base = blockIdx.x * CHUNK;
    for (int i = tid; i < CHUNK; i += 256) {
        int d = dst[base + i];
        int ss = src[base + i];
        float wi = w[base + i];
        unsigned wb = __float_as_uint(wi);
        int p = atomicAdd(&curd[d >> 8], 1);   // LDS atomic
        uint2 r; r.x = (unsigned)ss | ((unsigned)(d & 255) << 16); r.y = wb;
        dsw[p] = r;
        int q = atomicAdd(&curs[ss >> 8], 1);  // LDS atomic
        uint2 r2; r2.x = (unsigned)(ss & 255); r2.y = wb;
        ssw[q] = r2;
    }
}

// deg per src-bucket -> dinv
__global__ __launch_bounds__(256) void k_sdeg(const uint2* __restrict__ ssw,
                                              const int* __restrict__ bstart_s,
                                              float* __restrict__ dinv) {
    __shared__ float h[256];
    int tid = threadIdx.x;
    int b = blockIdx.x;
    h[tid] = 0.f;
    __syncthreads();
    int e0 = bstart_s[b], e1 = bstart_s[b + 1];
    for (int i = e0 + tid; i < e1; i += 256) {
        uint2 r = ssw[i];
        atomicAdd(&h[r.x & 255], __uint_as_float(r.y));  // LDS atomic
    }
    __syncthreads();
    int node = (b << 8) + tid;
    if (node < N_NODES) {
        float d = h[tid];
        dinv[node] = d > 0.f ? rsqrtf(fmaxf(d, 1e-30f)) : 0.f;
    }
}

// per-bucket CSR build + inline norm; csr entry = src(16b) | f16norm << 16
__global__ __launch_bounds__(256) void k_bcsr(const uint2* __restrict__ dsw,
                                              const int* __restrict__ bstart_d,
                                              const float* __restrict__ dinv,
                                              int* __restrict__ row_start,
                                              unsigned* __restrict__ csr4) {
    __shared__ int ncnt[256];
    __shared__ int cur[256];
    __shared__ int sc[256];
    __shared__ float ldinv[256];
    int tid = threadIdx.x;
    int b = blockIdx.x;
    int node = (b << 8) + tid;
    ncnt[tid] = 0;
    ldinv[tid] = (node < N_NODES) ? dinv[node] : 0.f;
    __syncthreads();
    int e0 = bstart_d[b], e1 = bstart_d[b + 1];
    for (int i = e0 + tid; i < e1; i += 256)
        atomicAdd(&ncnt[(dsw[i].x >> 16) & 255], 1);  // LDS atomic
    __syncthreads();
    int v = ncnt[tid];
    sc[tid] = v;
    __syncthreads();
    for (int off = 1; off < 256; off <<= 1) {
        int t = (tid >= off) ? sc[tid - off] : 0;
        __syncthreads();
        sc[tid] += t;
        __syncthreads();
    }
    int excl = sc[tid] - v;
    cur[tid] = excl;
    if (node < N_NODES) row_start[node] = e0 + excl;
    __syncthreads();
    for (int i = e0 + tid; i < e1; i += 256) {
        uint2 sw = dsw[i];
        int srcn = sw.x & 0xFFFF;
        int ld = (sw.x >> 16) & 255;
        int p = e0 + atomicAdd(&cur[ld], 1);  // LDS atomic
        float nv = -dinv[srcn] * __uint_as_float(sw.y) * ldinv[ld];
        HBits hb; hb.h = __float2half(nv);
        csr4[p] = (unsigned)srcn | ((unsigned)hb.u << 16);
    }
}

// x fp32 -> X f16 (N x 128 contiguous)
__global__ void k_cvt_x(const float* __restrict__ x, __half* __restrict__ X, int n4) {
    int i = blockIdx.x * blockDim.x + threadIdx.x;
    if (i < n4) {
        float4 v = *(const float4*)&x[(size_t)i * 4];
        f16x4 o;
        o[0] = (_Float16)v.x; o[1] = (_Float16)v.y;
        o[2] = (_Float16)v.z; o[3] = (_Float16)v.w;
        *(f16x4*)&X[(size_t)i * 4] = o;
    }
}

// Build combined transposed weights for one layer:
// Wt[n*128 + k], n in [0,3C): slice0 = 2*W2, slice1 = W1, slice2 = W0 - W2.
__global__ void k_wt(const float* __restrict__ W, __half* __restrict__ Wt, int C) {
    int i = blockIdx.x * blockDim.x + threadIdx.x;
    if (i < 3 * C * 128) {
        int n = i >> 7, k = i & 127;
        int slice = n / C, c = n % C;
        float v;
        if (slice == 0)      v = 2.f * W[(size_t)(256 + k) * C + c];
        else if (slice == 1) v = W[(size_t)(128 + k) * C + c];
        else                 v = W[(size_t)k * C + c] - W[(size_t)(256 + k) * C + c];
        Wt[i] = __float2half(v);
    }
}

// ---------- SpMM: one wave per node, full-width rows, multi-edge gathers ----
// R6-proven shape (52us @ FETCH 150MB): FW=128 -> 16 feature lanes x 4 edge
// groups, 8 gathers (32 edges) in flight; FW=64 -> 8 lanes x 8 groups, 4
// gathers. ALL strides compile-time (R7's runtime strides cost +10us VALU;
// R8's 16-feat XCD slicing thrashed L2 at line granularity - reverted).
// out[node] = (SIG ? sigmoid(acc + Add[node] + bias) : acc + Add[node])
template <int ST_IN, int ST_ADD, int ST_OUT, int FW, int SIG, int F32>
__global__ __launch_bounds__(256) void k_spmm(const __half* __restrict__ Xin,
                                              const __half* __restrict__ Add,
                                              void* __restrict__ outp,
                                              const float* __restrict__ bias,
                                              const int* __restrict__ row_start,
                                              const unsigned* __restrict__ csr4) {
    constexpr int NL = FW / 8;      // feature lanes per edge (16 or 8)
    constexpr int EG = 64 / NL;     // edge groups (4 or 8)
    constexpr int KE = 32 / EG;     // edges per lane per iter (8 or 4)
    int node = blockIdx.x * 4 + (threadIdx.x >> 6);
    int lane = threadIdx.x & 63;
    int eg = lane / NL;
    int fs = lane % NL;
    int s = row_start[node];
    int e = row_start[node + 1];
    const __half* Tbase = Xin + fs * 8;
    float acc[8];
    #pragma unroll
    for (int f = 0; f < 8; f++) acc[f] = 0.f;

    int j = s;
    for (; j + 32 <= e; j += 32) {
        unsigned mye = csr4[j + (lane & 31)];
        int sp[KE]; float nv[KE];
        #pragma unroll
        for (int k = 0; k < KE; k++) {
            unsigned ent = (unsigned)__shfl((int)mye, EG * k + eg);
            sp[k] = (int)(ent & 0xFFFFu);
            HBits hb; hb.u = (unsigned short)(ent >> 16);
            nv[k] = __half2float(hb.h);
        }
        f16x8 r[KE];
        #pragma unroll
        for (int k = 0; k < KE; k++)
            r[k] = *(const f16x8*)&Tbase[(size_t)sp[k] * ST_IN];
        #pragma unroll
        for (int k = 0; k < KE; k++)
            #pragma unroll
            for (int f = 0; f < 8; f++)
                acc[f] = fmaf(nv[k], (float)r[k][f], acc[f]);
    }
    int rem = e - j;
    if (rem > 0) {
        unsigned mye = csr4[j + min(lane & 31, rem - 1)];
        int sp[KE]; float nv[KE];
        #pragma unroll
        for (int k = 0; k < KE; k++) {
            int li = EG * k + eg;
            int sli = (li < rem) ? li : 0;
            unsigned ent = (unsigned)__shfl((int)mye, sli);
            sp[k] = (int)(ent & 0xFFFFu);
            HBits hb; hb.u = (unsigned short)(ent >> 16);
            float nvv = __half2float(hb.h);
            nv[k] = (li < rem) ? nvv : 0.f;
        }
        f16x8 r[KE];
        #pragma unroll
        for (int k = 0; k < KE; k++)
            r[k] = *(const f16x8*)&Tbase[(size_t)sp[k] * ST_IN];
        #pragma unroll
        for (int k = 0; k < KE; k++)
            #pragma unroll
            for (int f = 0; f < 8; f++)
                acc[f] = fmaf(nv[k], (float)r[k][f], acc[f]);
    }
    // reduce edge-group partials
    #pragma unroll
    for (int f = 0; f < 8; f++)
        for (int m = NL; m < 64; m <<= 1)
            acc[f] += __shfl_xor(acc[f], m);
    if (eg == 0) {
        f16x8 av = *(const f16x8*)&Add[(size_t)node * ST_ADD + fs * 8];
        float v[8];
        #pragma unroll
        for (int f = 0; f < 8; f++) v[f] = acc[f] + (float)av[f];
        if (SIG) {
            #pragma unroll
            for (int f = 0; f < 8; f++) {
                v[f] += bias[fs * 8 + f];
                v[f] = 1.f / (1.f + expf(-v[f]));
            }
        }
        if (F32) {
            float* o = (float*)outp + (size_t)node * ST_OUT + fs * 8;
            float4 o0; o0.x = v[0]; o0.y = v[1]; o0.z = v[2]; o0.w = v[3];
            float4 o1; o1.x = v[4]; o1.y = v[5]; o1.z = v[6]; o1.w = v[7];
            *(float4*)&o[0] = o0;
            *(float4*)&o[4] = o1;
        } else {
            f16x8 o;
            #pragma unroll
            for (int f = 0; f < 8; f++) o[f] = (_Float16)v[f];
            *(f16x8*)((__half*)outp + (size_t)node * ST_OUT + fs * 8) = o;
        }
    }
}

// ---------- MFMA GEMM: G[M x 3C] = X[M x 128] @ Wt^T, col-chunk CC per block.y
// mfma_f32_16x16x32_f16: A[m=lane&15][k=(lane>>4)*8+j]; C/D col=lane&15,row=(lane>>4)*4+r.
template <int CC>
__global__ __launch_bounds__(256) void k_gemm(const __half* __restrict__ A,
                                              const __half* __restrict__ Wt,
                                              __half* __restrict__ G, int M) {
    constexpr int NF = CC / 16;
    constexpr int N3 = 3 * CC;
    __shared__ _Float16 As[64][56];
    __shared__ _Float16 Bs[CC][56];
    int tid = threadIdx.x;
    int wave = tid >> 6, lane = tid & 63;
    int lm = lane & 15, lq = lane >> 4;
    int m0 = blockIdx.x * 64;
    int n0 = blockIdx.y * CC;
    f32x4 acc[NF];
    for (int nf = 0; nf < NF; nf++) acc[nf] = (f32x4)0.0f;

    for (int k0 = 0; k0 < 128; k0 += 32) {
        {
            int r = tid >> 2, q = tid & 3;
            int row = m0 + r;
            if (row >= M) row = M - 1;
            *(f16x8*)&As[r][q * 8] = *(const f16x8*)&A[(size_t)row * 128 + k0 + q * 8];
        }
        for (int i = 0; i < CC / 64; i++) {
            int idx = tid + i * 256;
            int n = idx >> 2, q = idx & 3;
            *(f16x8*)&Bs[n][q * 8] = *(const f16x8*)&Wt[(size_t)(n0 + n) * 128 + k0 + q * 8];
        }
        __syncthreads();
        f16x8 a = *(const f16x8*)&As[wave * 16 + lm][lq * 8];
        for (int nf = 0; nf < NF; nf++) {
            f16x8 b = *(const f16x8*)&Bs[nf * 16 + lm][lq * 8];
            acc[nf] = __builtin_amdgcn_mfma_f32_16x16x32_f16(a, b, acc[nf], 0, 0, 0);
        }
        __syncthreads();
    }
    for (int nf = 0; nf < NF; nf++) {
        for (int r = 0; r < 4; r++) {
            int grow = m0 + wave * 16 + lq * 4 + r;
            int col = n0 + nf * 16 + lm;
            if (grow < M)
                G[(size_t)grow * N3 + col] = __float2half(acc[nf][r]);
        }
    }
}

extern "C" void kernel_launch(void* const* d_in, const int* in_sizes, int n_in,
                              void* d_out, int out_size, void* d_ws, size_t ws_size,
                              hipStream_t stream) {
    const float* x  = (const float*)d_in[0];
    const int*   ei = (const int*)d_in[1];
    const float* ew = (const float*)d_in[2];
    const float* W0 = (const float*)d_in[3];
    const float* b0 = (const float*)d_in[4];
    const float* W1 = (const float*)d_in[5];
    const float* b1 = (const float*)d_in[6];
    const float* W2 = (const float*)d_in[7];
    const float* b2 = (const float*)d_in[8];
    const int* src = ei;
    const int* dst = ei + N_EDGES;

    char* ws = (char*)d_ws;
    size_t off = 0;
    auto alloc = [&](size_t bytes) -> char* {
        size_t p = (off + 255) & ~(size_t)255;
        off = p + bytes;
        return ws + p;
    };
    __half*   X      = (__half*)alloc((size_t)N_NODES * 128 * 2);
    __half*   G      = (__half*)alloc((size_t)N_NODES * 384 * 2);   // [P|Q|S] per layer
    __half*   TMP    = (__half*)alloc((size_t)N_NODES * 128 * 2);   // L*P + Q
    unsigned* csr4   = (unsigned*)alloc((size_t)N_EDGES * 4);       // src | f16norm<<16
    uint2*    dsw    = (uint2*)alloc((size_t)N_EDGES * 8);
    uint2*    ssw    = (uint2*)alloc((size_t)N_EDGES * 8);
    int*      bcnt_d = (int*)alloc((size_t)EBLK * 256 * 4);
    int*      bcnt_s = (int*)alloc((size_t)EBLK * 256 * 4);
    int*      btot   = (int*)alloc(512 * 4);
    int*      bstart_d = (int*)alloc(257 * 4);
    int*      bstart_s = (int*)alloc(257 * 4);
    int*      row_start= (int*)alloc((size_t)(N_NODES + 1) * 4);
    float*    dinv   = (float*)alloc((size_t)N_NODES * 4);
    __half*   Wt0    = (__half*)alloc((size_t)384 * 128 * 2);
    __half*   Wt1    = (__half*)alloc((size_t)384 * 128 * 2);
    __half*   Wt2    = (__half*)alloc((size_t)192 * 128 * 2);

    // dual bucket sort; zero device-scope atomics anywhere
    k_bcount<<<EBLK, 256, 0, stream>>>(src, dst, bcnt_d, bcnt_s);
    k_bscan1<<<512, 256, 0, stream>>>(bcnt_d, bcnt_s, btot);
    k_bscan2<<<1, 256, 0, stream>>>(btot, bstart_d, bstart_s, row_start);
    k_bscatter<<<EBLK, 256, 0, stream>>>(src, dst, ew, bcnt_d, bcnt_s,
                                         bstart_d, bstart_s, dsw, ssw);
    k_sdeg<<<NBUCK, 256, 0, stream>>>(ssw, bstart_s, dinv);
    k_bcsr<<<NBUCK, 256, 0, stream>>>(dsw, bstart_d, dinv, row_start, csr4);

    k_cvt_x<<<(N_NODES * 32 + 255) / 256, 256, 0, stream>>>(x, X, N_NODES * 32);
    k_wt<<<(3 * 128 * 128 + 255) / 256, 256, 0, stream>>>(W0, Wt0, 128);
    k_wt<<<(3 * 128 * 128 + 255) / 256, 256, 0, stream>>>(W1, Wt1, 128);
    k_wt<<<(3 * 64 * 128 + 255) / 256, 256, 0, stream>>>(W2, Wt2, 64);

    int gb = (N_NODES + 63) / 64;   // 782
    int sb = N_NODES / 4;           // 12500
    // layer 0: G = X @ [Wc|Wb|Wa];  TMP = L*P + Q;  X = sigmoid(L*TMP + S + b0)
    k_gemm<128><<<dim3(gb, 3), 256, 0, stream>>>(X, Wt0, G, N_NODES);
    k_spmm<384, 384, 128, 128, 0, 0><<<sb, 256, 0, stream>>>(G, G + 128, TMP,
                                                             nullptr, row_start, csr4);
    k_spmm<128, 384, 128, 128, 1, 0><<<sb, 256, 0, stream>>>(TMP, G + 256, X,
                                                             b0, row_start, csr4);
    // layer 1
    k_gemm<128><<<dim3(gb, 3), 256, 0, stream>>>(X, Wt1, G, N_NODES);
    k_spmm<384, 384, 128, 128, 0, 0><<<sb, 256, 0, stream>>>(G, G + 128, TMP,
                                                             nullptr, row_start, csr4);
    k_spmm<128, 384, 128, 128, 1, 0><<<sb, 256, 0, stream>>>(TMP, G + 256, X,
                                                             b1, row_start, csr4);
    // layer 2 (C=64): G = N x 192
    k_gemm<64><<<dim3(gb, 3), 256, 0, stream>>>(X, Wt2, G, N_NODES);
    k_spmm<192, 192, 64, 64, 0, 0><<<sb, 256, 0, stream>>>(G, G + 64, TMP,
                                                           nullptr, row_start, csr4);
    k_spmm<64, 192, 64, 64, 1, 1><<<sb, 256, 0, stream>>>(TMP, G + 128, d_out,
                                                          b2, row_start, csr4);
}

// Round 11
// 507.806 us; speedup vs baseline: 2.8637x; 1.0309x over previous
//
#include <hip/hip_runtime.h>
#include <hip/hip_fp16.h>
#include <math.h>

#define N_NODES 50000
#define N_EDGES 1600000
#define NBUCK 196          // node >> 8 buckets (50000/256)
#define EBLK 400           // edge blocks for sort
#define CHUNK 4000         // edges per block (EBLK*CHUNK == N_EDGES)

typedef _Float16 f16x8 __attribute__((ext_vector_type(8)));
typedef _Float16 f16x4 __attribute__((ext_vector_type(4)));
typedef _Float16 f16x2 __attribute__((ext_vector_type(2)));
typedef float f32x4 __attribute__((ext_vector_type(4)));

union HBits { __half h; unsigned short u; };

// ---------- dual bucket sort (dst-keyed for CSR, src-keyed for deg) ----------
__global__ __launch_bounds__(256) void k_bcount(const int* __restrict__ src,
                                                const int* __restrict__ dst,
                                                int* __restrict__ bcnt_d,
                                                int* __restrict__ bcnt_s) {
    __shared__ int lcd[256];
    __shared__ int lcs[256];
    int tid = threadIdx.x;
    lcd[tid] = 0; lcs[tid] = 0;
    __syncthreads();
    int base = blockIdx.x * CHUNK;
    for (int i = tid; i < CHUNK; i += 256) {
        atomicAdd(&lcd[dst[base + i] >> 8], 1);
        atomicAdd(&lcs[src[base + i] >> 8], 1);
    }
    __syncthreads();
    bcnt_d[blockIdx.x * 256 + tid] = lcd[tid];
    bcnt_s[blockIdx.x * 256 + tid] = lcs[tid];
}

// per-bucket scan over edge-blocks (parallel)
__global__ __launch_bounds__(256) void k_bscan1(int* __restrict__ bcnt_d,
                                                int* __restrict__ bcnt_s,
                                                int* __restrict__ btot) {
    int b = blockIdx.x & 255;
    int* bcnt = (blockIdx.x >> 8) ? bcnt_s : bcnt_d;
    int tid = threadIdx.x;
    int k0 = 2 * tid;
    int v0 = (k0 < EBLK) ? bcnt[k0 * 256 + b] : 0;
    int v1 = (k0 + 1 < EBLK) ? bcnt[(k0 + 1) * 256 + b] : 0;
    int pair = v0 + v1;
    __shared__ int s[256];
    s[tid] = pair;
    __syncthreads();
    for (int off = 1; off < 256; off <<= 1) {
        int t = (tid >= off) ? s[tid - off] : 0;
        __syncthreads();
        s[tid] += t;
        __syncthreads();
    }
    int excl = s[tid] - pair;
    if (k0 < EBLK)     bcnt[k0 * 256 + b] = excl;
    if (k0 + 1 < EBLK) bcnt[(k0 + 1) * 256 + b] = excl + v0;
    if (tid == 255) btot[(blockIdx.x >> 8) * 256 + b] = s[255];
}

__global__ __launch_bounds__(256) void k_bscan2(const int* __restrict__ btot,
                                                int* __restrict__ bstart_d,
                                                int* __restrict__ bstart_s,
                                                int* __restrict__ row_start) {
    __shared__ int s[256];
    int b = threadIdx.x;
    int v = btot[b];
    s[b] = v;
    __syncthreads();
    for (int off = 1; off < 256; off <<= 1) {
        int t = (b >= off) ? s[b - off] : 0;
        __syncthreads();
        s[b] += t;
        __syncthreads();
    }
    bstart_d[b] = s[b] - v;
    if (b == 0) {
        bstart_d[256] = N_EDGES;
        row_start[N_NODES] = N_EDGES;
    }
    __syncthreads();
    int v2 = btot[256 + b];
    s[b] = v2;
    __syncthreads();
    for (int off = 1; off < 256; off <<= 1) {
        int t = (b >= off) ? s[b - off] : 0;
        __syncthreads();
        s[b] += t;
        __syncthreads();
    }
    bstart_s[b] = s[b] - v2;
    if (b == 0) bstart_s[256] = N_EDGES;
}

// scatter packed records into both sorted orders (LDS cursors only)
__global__ __launch_bounds__(256) void k_bscatter(const int* __restrict__ src,
                                                  const int* __restrict__ dst,
                                                  const float* __restrict__ w,
                                                  const int* __restrict__ bcnt_d,
                                                  const int* __restrict__ bcnt_s,
                                                  const int* __restrict__ bstart_d,
                                                  const int* __restrict__ bstart_s,
                                                  uint2* __restrict__ dsw,
                                                  uint2* __restrict__ ssw) {
    __shared__ int curd[256];
    __shared__ int curs[256];
    int tid = threadIdx.x;
    curd[tid] = bcnt_d[blockIdx.x * 256 + tid] + bstart_d[tid];
    curs[tid] = bcnt_s[blockIdx.x * 256 + tid] + bstart_s[tid];
    __syncthreads();
    int base = blockIdx.x * CHUNK;
    for (int i = tid; i < CHUNK; i += 256) {
        int d = dst[base + i];
        int ss = src[base + i];
        float wi = w[base + i];
        unsigned wb = __float_as_uint(wi);
        int p = atomicAdd(&curd[d >> 8], 1);   // LDS atomic
        uint2 r; r.x = (unsigned)ss | ((unsigned)(d & 255) << 16); r.y = wb;
        dsw[p] = r;
        int q = atomicAdd(&curs[ss >> 8], 1);  // LDS atomic
        uint2 r2; r2.x = (unsigned)(ss & 255); r2.y = wb;
        ssw[q] = r2;
    }
}

// deg per src-bucket -> dinv
__global__ __launch_bounds__(256) void k_sdeg(const uint2* __restrict__ ssw,
                                              const int* __restrict__ bstart_s,
                                              float* __restrict__ dinv) {
    __shared__ float h[256];
    int tid = threadIdx.x;
    int b = blockIdx.x;
    h[tid] = 0.f;
    __syncthreads();
    int e0 = bstart_s[b], e1 = bstart_s[b + 1];
    for (int i = e0 + tid; i < e1; i += 256) {
        uint2 r = ssw[i];
        atomicAdd(&h[r.x & 255], __uint_as_float(r.y));  // LDS atomic
    }
    __syncthreads();
    int node = (b << 8) + tid;
    if (node < N_NODES) {
        float d = h[tid];
        dinv[node] = d > 0.f ? rsqrtf(fmaxf(d, 1e-30f)) : 0.f;
    }
}

// per-bucket CSR build + inline norm; csr entry = src(16b) | f16norm << 16
__global__ __launch_bounds__(256) void k_bcsr(const uint2* __restrict__ dsw,
                                              const int* __restrict__ bstart_d,
                                              const float* __restrict__ dinv,
                                              int* __restrict__ row_start,
                                              unsigned* __restrict__ csr4) {
    __shared__ int ncnt[256];
    __shared__ int cur[256];
    __shared__ int sc[256];
    __shared__ float ldinv[256];
    int tid = threadIdx.x;
    int b = blockIdx.x;
    int node = (b << 8) + tid;
    ncnt[tid] = 0;
    ldinv[tid] = (node < N_NODES) ? dinv[node] : 0.f;
    __syncthreads();
    int e0 = bstart_d[b], e1 = bstart_d[b + 1];
    for (int i = e0 + tid; i < e1; i += 256)
        atomicAdd(&ncnt[(dsw[i].x >> 16) & 255], 1);  // LDS atomic
    __syncthreads();
    int v = ncnt[tid];
    sc[tid] = v;
    __syncthreads();
    for (int off = 1; off < 256; off <<= 1) {
        int t = (tid >= off) ? sc[tid - off] : 0;
        __syncthreads();
        sc[tid] += t;
        __syncthreads();
    }
    int excl = sc[tid] - v;
    cur[tid] = excl;
    if (node < N_NODES) row_start[node] = e0 + excl;
    __syncthreads();
    for (int i = e0 + tid; i < e1; i += 256) {
        uint2 sw = dsw[i];
        int srcn = sw.x & 0xFFFF;
        int ld = (sw.x >> 16) & 255;
        int p = e0 + atomicAdd(&cur[ld], 1);  // LDS atomic
        float nv = -dinv[srcn] * __uint_as_float(sw.y) * ldinv[ld];
        HBits hb; hb.h = __float2half(nv);
        csr4[p] = (unsigned)srcn | ((unsigned)hb.u << 16);
    }
}

// x fp32 -> X f16 (N x 128 contiguous)
__global__ void k_cvt_x(const float* __restrict__ x, __half* __restrict__ X, int n4) {
    int i = blockIdx.x * blockDim.x + threadIdx.x;
    if (i < n4) {
        float4 v = *(const float4*)&x[(size_t)i * 4];
        f16x4 o;
        o[0] = (_Float16)v.x; o[1] = (_Float16)v.y;
        o[2] = (_Float16)v.z; o[3] = (_Float16)v.w;
        *(f16x4*)&X[(size_t)i * 4] = o;
    }
}

// Build combined transposed weights for one layer:
// Wt[n*128 + k], n in [0,3C): slice0 = 2*W2, slice1 = W1, slice2 = W0 - W2.
__global__ void k_wt(const float* __restrict__ W, __half* __restrict__ Wt, int C) {
    int i = blockIdx.x * blockDim.x + threadIdx.x;
    if (i < 3 * C * 128) {
        int n = i >> 7, k = i & 127;
        int slice = n / C, c = n % C;
        float v;
        if (slice == 0)      v = 2.f * W[(size_t)(256 + k) * C + c];
        else if (slice == 1) v = W[(size_t)(128 + k) * C + c];
        else                 v = W[(size_t)k * C + c] - W[(size_t)(256 + k) * C + c];
        Wt[i] = __float2half(v);
    }
}

// ---------- SpMM: one wave per node, edge-PAIR dot2 MAC core ----------
// R6 gather shape (FW=128: 16 feat lanes x 4 edge groups, 8 gathers in
// flight). R10: edges processed in pairs - norms stay f16 (packed f16x2
// straight from csr high halves, no f32 cvt), MAC = v_pack_b32_f16 +
// v_dot2_f32_f16 per feature-pair (2 VALU vs 4 for cvt+fma) [R9: VALUBusy
// 67%, VALU time ~43us comparable to fetch ~57us - VALU cut is the lever].
// All strides compile-time. out = SIG ? sigmoid(acc+Add+bias) : acc+Add.
template <int ST_IN, int ST_ADD, int ST_OUT, int FW, int SIG, int F32>
__global__ __launch_bounds__(256) void k_spmm(const __half* __restrict__ Xin,
                                              const __half* __restrict__ Add,
                                              void* __restrict__ outp,
                                              const float* __restrict__ bias,
                                              const int* __restrict__ row_start,
                                              const unsigned* __restrict__ csr4) {
    constexpr int NL = FW / 8;      // feature lanes per edge (16 or 8)
    constexpr int EG = 64 / NL;     // edge groups (4 or 8)
    constexpr int KP = 16 / EG;     // edge PAIRS per group per iter (4 or 2)
    int node = blockIdx.x * 4 + (threadIdx.x >> 6);
    int lane = threadIdx.x & 63;
    int eg = lane / NL;
    int fs = lane % NL;
    int s = row_start[node];
    int e = row_start[node + 1];
    const __half* Tbase = Xin + fs * 8;
    float acc[8];
    #pragma unroll
    for (int f = 0; f < 8; f++) acc[f] = 0.f;

    int j = s;
    for (; j + 32 <= e; j += 32) {
        unsigned mye = csr4[j + (lane & 31)];
        int sp0[KP], sp1[KP]; f16x2 nv2[KP];
        #pragma unroll
        for (int k = 0; k < KP; k++) {
            unsigned ea = (unsigned)__shfl((int)mye, EG * (2 * k) + eg);
            unsigned eb = (unsigned)__shfl((int)mye, EG * (2 * k + 1) + eg);
            sp0[k] = (int)(ea & 0xFFFFu);
            sp1[k] = (int)(eb & 0xFFFFu);
            unsigned np = (ea >> 16) | (eb & 0xFFFF0000u);
            __builtin_memcpy(&nv2[k], &np, 4);
        }
        f16x8 r0[KP], r1[KP];
        #pragma unroll
        for (int k = 0; k < KP; k++) {
            r0[k] = *(const f16x8*)&Tbase[(size_t)sp0[k] * ST_IN];
            r1[k] = *(const f16x8*)&Tbase[(size_t)sp1[k] * ST_IN];
        }
        #pragma unroll
        for (int k = 0; k < KP; k++) {
            #pragma unroll
            for (int f = 0; f < 8; f++) {
                f16x2 h; h[0] = r0[k][f]; h[1] = r1[k][f];
                acc[f] = __builtin_amdgcn_fdot2(h, nv2[k], acc[f], false);
            }
        }
    }
    int rem = e - j;
    if (rem > 0) {
        unsigned mye = csr4[j + min(lane & 31, rem - 1)];
        int sp0[KP], sp1[KP]; f16x2 nv2[KP];
        #pragma unroll
        for (int k = 0; k < KP; k++) {
            int li0 = EG * (2 * k) + eg;
            int li1 = EG * (2 * k + 1) + eg;
            unsigned ea = (unsigned)__shfl((int)mye, (li0 < rem) ? li0 : 0);
            unsigned eb = (unsigned)__shfl((int)mye, (li1 < rem) ? li1 : 0);
            sp0[k] = (int)(ea & 0xFFFFu);
            sp1[k] = (int)(eb & 0xFFFFu);
            unsigned np = (ea >> 16) | (eb & 0xFFFF0000u);
            if (li0 >= rem) np &= 0xFFFF0000u;
            if (li1 >= rem) np &= 0x0000FFFFu;
            __builtin_memcpy(&nv2[k], &np, 4);
        }
        f16x8 r0[KP], r1[KP];
        #pragma unroll
        for (int k = 0; k < KP; k++) {
            r0[k] = *(const f16x8*)&Tbase[(size_t)sp0[k] * ST_IN];
            r1[k] = *(const f16x8*)&Tbase[(size_t)sp1[k] * ST_IN];
        }
        #pragma unroll
        for (int k = 0; k < KP; k++) {
            #pragma unroll
            for (int f = 0; f < 8; f++) {
                f16x2 h; h[0] = r0[k][f]; h[1] = r1[k][f];
                acc[f] = __builtin_amdgcn_fdot2(h, nv2[k], acc[f], false);
            }
        }
    }
    // reduce edge-group partials
    #pragma unroll
    for (int f = 0; f < 8; f++)
        for (int m = NL; m < 64; m <<= 1)
            acc[f] += __shfl_xor(acc[f], m);
    if (eg == 0) {
        f16x8 av = *(const f16x8*)&Add[(size_t)node * ST_ADD + fs * 8];
        float v[8];
        #pragma unroll
        for (int f = 0; f < 8; f++) v[f] = acc[f] + (float)av[f];
        if (SIG) {
            #pragma unroll
            for (int f = 0; f < 8; f++) {
                v[f] += bias[fs * 8 + f];
                v[f] = 1.f / (1.f + expf(-v[f]));
            }
        }
        if (F32) {
            float* o = (float*)outp + (size_t)node * ST_OUT + fs * 8;
            float4 o0; o0.x = v[0]; o0.y = v[1]; o0.z = v[2]; o0.w = v[3];
            float4 o1; o1.x = v[4]; o1.y = v[5]; o1.z = v[6]; o1.w = v[7];
            *(float4*)&o[0] = o0;
            *(float4*)&o[4] = o1;
        } else {
            f16x8 o;
            #pragma unroll
            for (int f = 0; f < 8; f++) o[f] = (_Float16)v[f];
            *(f16x8*)((__half*)outp + (size_t)node * ST_OUT + fs * 8) = o;
        }
    }
}

// ---------- MFMA GEMM: G[M x 3C] = X[M x 128] @ Wt^T, col-chunk CC per block.y
// mfma_f32_16x16x32_f16: A[m=lane&15][k=(lane>>4)*8+j]; C/D col=lane&15,row=(lane>>4)*4+r.
template <int CC>
__global__ __launch_bounds__(256) void k_gemm(const __half* __restrict__ A,
                                              const __half* __restrict__ Wt,
                                              __half* __restrict__ G, int M) {
    constexpr int NF = CC / 16;
    constexpr int N3 = 3 * CC;
    __shared__ _Float16 As[64][56];
    __shared__ _Float16 Bs[CC][56];
    int tid = threadIdx.x;
    int wave = tid >> 6, lane = tid & 63;
    int lm = lane & 15, lq = lane >> 4;
    int m0 = blockIdx.x * 64;
    int n0 = blockIdx.y * CC;
    f32x4 acc[NF];
    for (int nf = 0; nf < NF; nf++) acc[nf] = (f32x4)0.0f;

    for (int k0 = 0; k0 < 128; k0 += 32) {
        {
            int r = tid >> 2, q = tid & 3;
            int row = m0 + r;
            if (row >= M) row = M - 1;
            *(f16x8*)&As[r][q * 8] = *(const f16x8*)&A[(size_t)row * 128 + k0 + q * 8];
        }
        for (int i = 0; i < CC / 64; i++) {
            int idx = tid + i * 256;
            int n = idx >> 2, q = idx & 3;
            *(f16x8*)&Bs[n][q * 8] = *(const f16x8*)&Wt[(size_t)(n0 + n) * 128 + k0 + q * 8];
        }
        __syncthreads();
        f16x8 a = *(const f16x8*)&As[wave * 16 + lm][lq * 8];
        for (int nf = 0; nf < NF; nf++) {
            f16x8 b = *(const f16x8*)&Bs[nf * 16 + lm][lq * 8];
            acc[nf] = __builtin_amdgcn_mfma_f32_16x16x32_f16(a, b, acc[nf], 0, 0, 0);
        }
        __syncthreads();
    }
    for (int nf = 0; nf < NF; nf++) {
        for (int r = 0; r < 4; r++) {
            int grow = m0 + wave * 16 + lq * 4 + r;
            int col = n0 + nf * 16 + lm;
            if (grow < M)
                G[(size_t)grow * N3 + col] = __float2half(acc[nf][r]);
        }
    }
}

extern "C" void kernel_launch(void* const* d_in, const int* in_sizes, int n_in,
                              void* d_out, int out_size, void* d_ws, size_t ws_size,
                              hipStream_t stream) {
    const float* x  = (const float*)d_in[0];
    const int*   ei = (const int*)d_in[1];
    const float* ew = (const float*)d_in[2];
    const float* W0 = (const float*)d_in[3];
    const float* b0 = (const float*)d_in[4];
    const float* W1 = (const float*)d_in[5];
    const float* b1 = (const float*)d_in[6];
    const float* W2 = (const float*)d_in[7];
    const float* b2 = (const float*)d_in[8];
    const int* src = ei;
    const int* dst = ei + N_EDGES;

    char* ws = (char*)d_ws;
    size_t off = 0;
    auto alloc = [&](size_t bytes) -> char* {
        size_t p = (off + 255) & ~(size_t)255;
        off = p + bytes;
        return ws + p;
    };
    __half*   X      = (__half*)alloc((size_t)N_NODES * 128 * 2);
    __half*   G      = (__half*)alloc((size_t)N_NODES * 384 * 2);   // [P|Q|S] per layer
    __half*   TMP    = (__half*)alloc((size_t)N_NODES * 128 * 2);   // L*P + Q
    unsigned* csr4   = (unsigned*)alloc((size_t)N_EDGES * 4);       // src | f16norm<<16
    uint2*    dsw    = (uint2*)alloc((size_t)N_EDGES * 8);
    uint2*    ssw    = (uint2*)alloc((size_t)N_EDGES * 8);
    int*      bcnt_d = (int*)alloc((size_t)EBLK * 256 * 4);
    int*      bcnt_s = (int*)alloc((size_t)EBLK * 256 * 4);
    int*      btot   = (int*)alloc(512 * 4);
    int*      bstart_d = (int*)alloc(257 * 4);
    int*      bstart_s = (int*)alloc(257 * 4);
    int*      row_start= (int*)alloc((size_t)(N_NODES + 1) * 4);
    float*    dinv   = (float*)alloc((size_t)N_NODES * 4);
    __half*   Wt0    = (__half*)alloc((size_t)384 * 128 * 2);
    __half*   Wt1    = (__half*)alloc((size_t)384 * 128 * 2);
    __half*   Wt2    = (__half*)alloc((size_t)192 * 128 * 2);

    // dual bucket sort; zero device-scope atomics anywhere
    k_bcount<<<EBLK, 256, 0, stream>>>(src, dst, bcnt_d, bcnt_s);
    k_bscan1<<<512, 256, 0, stream>>>(bcnt_d, bcnt_s, btot);
    k_bscan2<<<1, 256, 0, stream>>>(btot, bstart_d, bstart_s, row_start);
    k_bscatter<<<EBLK, 256, 0, stream>>>(src, dst, ew, bcnt_d, bcnt_s,
                                         bstart_d, bstart_s, dsw, ssw);
    k_sdeg<<<NBUCK, 256, 0, stream>>>(ssw, bstart_s, dinv);
    k_bcsr<<<NBUCK, 256, 0, stream>>>(dsw, bstart_d, dinv, row_start, csr4);

    k_cvt_x<<<(N_NODES * 32 + 255) / 256, 256, 0, stream>>>(x, X, N_NODES * 32);
    k_wt<<<(3 * 128 * 128 + 255) / 256, 256, 0, stream>>>(W0, Wt0, 128);
    k_wt<<<(3 * 128 * 128 + 255) / 256, 256, 0, stream>>>(W1, Wt1, 128);
    k_wt<<<(3 * 64 * 128 + 255) / 256, 256, 0, stream>>>(W2, Wt2, 64);

    int gb = (N_NODES + 63) / 64;   // 782
    int sb = N_NODES / 4;           // 12500
    // layer 0: G = X @ [Wc|Wb|Wa];  TMP = L*P + Q;  X = sigmoid(L*TMP + S + b0)
    k_gemm<128><<<dim3(gb, 3), 256, 0, stream>>>(X, Wt0, G, N_NODES);
    k_spmm<384, 384, 128, 128, 0, 0><<<sb, 256, 0, stream>>>(G, G + 128, TMP,
                                                             nullptr, row_start, csr4);
    k_spmm<128, 384, 128, 128, 1, 0><<<sb, 256, 0, stream>>>(TMP, G + 256, X,
                                                             b0, row_start, csr4);
    // layer 1
    k_gemm<128><<<dim3(gb, 3), 256, 0, stream>>>(X, Wt1, G, N_NODES);
    k_spmm<384, 384, 128, 128, 0, 0><<<sb, 256, 0, stream>>>(G, G + 128, TMP,
                                                             nullptr, row_start, csr4);
    k_spmm<128, 384, 128, 128, 1, 0><<<sb, 256, 0, stream>>>(TMP, G + 256, X,
                                                             b1, row_start, csr4);
    // layer 2 (C=64): G = N x 192
    k_gemm<64><<<dim3(gb, 3), 256, 0, stream>>>(X, Wt2, G, N_NODES);
    k_spmm<192, 192, 64, 64, 0, 0><<<sb, 256, 0, stream>>>(G, G + 64, TMP,
                                                           nullptr, row_start, csr4);
    k_spmm<64, 192, 64, 64, 1, 1><<<sb, 256, 0, stream>>>(TMP, G + 128, d_out,
                                                          b2, row_start, csr4);
}

// Round 12
// 494.588 us; speedup vs baseline: 2.9402x; 1.0267x over previous
//
#include <hip/hip_runtime.h>
#include <hip/hip_fp16.h>
#include <math.h>

#define N_NODES 50000
#define N_EDGES 1600000
#define NBUCK 196          // node >> 8 buckets (50000/256)
#define EBLK 400           // edge blocks for sort
#define CHUNK 4000         // edges per block (EBLK*CHUNK == N_EDGES)

typedef _Float16 f16x8 __attribute__((ext_vector_type(8)));
typedef _Float16 f16x4 __attribute__((ext_vector_type(4)));
typedef _Float16 f16x2 __attribute__((ext_vector_type(2)));
typedef float f32x4 __attribute__((ext_vector_type(4)));

union HBits { __half h; unsigned short u; };

// ---------- dual bucket sort (dst-keyed for CSR, src-keyed for deg) ----------
__global__ __launch_bounds__(256) void k_bcount(const int* __restrict__ src,
                                                const int* __restrict__ dst,
                                                int* __restrict__ bcnt_d,
                                                int* __restrict__ bcnt_s) {
    __shared__ int lcd[256];
    __shared__ int lcs[256];
    int tid = threadIdx.x;
    lcd[tid] = 0; lcs[tid] = 0;
    __syncthreads();
    int base = blockIdx.x * CHUNK;
    for (int i = tid; i < CHUNK; i += 256) {
        atomicAdd(&lcd[dst[base + i] >> 8], 1);
        atomicAdd(&lcs[src[base + i] >> 8], 1);
    }
    __syncthreads();
    bcnt_d[blockIdx.x * 256 + tid] = lcd[tid];
    bcnt_s[blockIdx.x * 256 + tid] = lcs[tid];
}

// per-bucket scan over edge-blocks (parallel)
__global__ __launch_bounds__(256) void k_bscan1(int* __restrict__ bcnt_d,
                                                int* __restrict__ bcnt_s,
                                                int* __restrict__ btot) {
    int b = blockIdx.x & 255;
    int* bcnt = (blockIdx.x >> 8) ? bcnt_s : bcnt_d;
    int tid = threadIdx.x;
    int k0 = 2 * tid;
    int v0 = (k0 < EBLK) ? bcnt[k0 * 256 + b] : 0;
    int v1 = (k0 + 1 < EBLK) ? bcnt[(k0 + 1) * 256 + b] : 0;
    int pair = v0 + v1;
    __shared__ int s[256];
    s[tid] = pair;
    __syncthreads();
    for (int off = 1; off < 256; off <<= 1) {
        int t = (tid >= off) ? s[tid - off] : 0;
        __syncthreads();
        s[tid] += t;
        __syncthreads();
    }
    int excl = s[tid] - pair;
    if (k0 < EBLK)     bcnt[k0 * 256 + b] = excl;
    if (k0 + 1 < EBLK) bcnt[(k0 + 1) * 256 + b] = excl + v0;
    if (tid == 255) btot[(blockIdx.x >> 8) * 256 + b] = s[255];
}

__global__ __launch_bounds__(256) void k_bscan2(const int* __restrict__ btot,
                                                int* __restrict__ bstart_d,
                                                int* __restrict__ bstart_s,
                                                int* __restrict__ row_start) {
    __shared__ int s[256];
    int b = threadIdx.x;
    int v = btot[b];
    s[b] = v;
    __syncthreads();
    for (int off = 1; off < 256; off <<= 1) {
        int t = (b >= off) ? s[b - off] : 0;
        __syncthreads();
        s[b] += t;
        __syncthreads();
    }
    bstart_d[b] = s[b] - v;
    if (b == 0) {
        bstart_d[256] = N_EDGES;
        row_start[N_NODES] = N_EDGES;
    }
    __syncthreads();
    int v2 = btot[256 + b];
    s[b] = v2;
    __syncthreads();
    for (int off = 1; off < 256; off <<= 1) {
        int t = (b >= off) ? s[b - off] : 0;
        __syncthreads();
        s[b] += t;
        __syncthreads();
    }
    bstart_s[b] = s[b] - v2;
    if (b == 0) bstart_s[256] = N_EDGES;
}

// scatter packed records into both sorted orders (LDS cursors only)
// dsw: {src | dst_local<<16, f32 w}; ssw: src_local | f16w<<16 (4 B)
__global__ __launch_bounds__(256) void k_bscatter(const int* __restrict__ src,
                                                  const int* __restrict__ dst,
                                                  const float* __restrict__ w,
                                                  const int* __restrict__ bcnt_d,
                                                  const int* __restrict__ bcnt_s,
                                                  const int* __restrict__ bstart_d,
                                                  const int* __restrict__ bstart_s,
                                                  uint2* __restrict__ dsw,
                                                  unsigned* __restrict__ ssw) {
    __shared__ int curd[256];
    __shared__ int curs[256];
    int tid = threadIdx.x;
    curd[tid] = bcnt_d[blockIdx.x * 256 + tid] + bstart_d[tid];
    curs[tid] = bcnt_s[blockIdx.x * 256 + tid] + bstart_s[tid];
    __syncthreads();
    int base = blockIdx.x * CHUNK;
    for (int i = tid; i < CHUNK; i += 256) {
        int d = dst[base + i];
        int ss = src[base + i];
        float wi = w[base + i];
        int p = atomicAdd(&curd[d >> 8], 1);   // LDS atomic
        uint2 r; r.x = (unsigned)ss | ((unsigned)(d & 255) << 16);
        r.y = __float_as_uint(wi);
        dsw[p] = r;
        int q = atomicAdd(&curs[ss >> 8], 1);  // LDS atomic
        HBits hw; hw.h = __float2half(wi);
        ssw[q] = (unsigned)(ss & 255) | ((unsigned)hw.u << 16);
    }
}

// deg per src-bucket -> dinv (f16 w partials: ~0.05% deg error, negligible)
__global__ __launch_bounds__(256) void k_sdeg(const unsigned* __restrict__ ssw,
                                              const int* __restrict__ bstart_s,
                                              float* __restrict__ dinv) {
    __shared__ float h[256];
    int tid = threadIdx.x;
    int b = blockIdx.x;
    h[tid] = 0.f;
    __syncthreads();
    int e0 = bstart_s[b], e1 = bstart_s[b + 1];
    for (int i = e0 + tid; i < e1; i += 256) {
        unsigned r = ssw[i];
        HBits hb; hb.u = (unsigned short)(r >> 16);
        atomicAdd(&h[r & 255], __half2float(hb.h));  // LDS atomic
    }
    __syncthreads();
    int node = (b << 8) + tid;
    if (node < N_NODES) {
        float d = h[tid];
        dinv[node] = d > 0.f ? rsqrtf(fmaxf(d, 1e-30f)) : 0.f;
    }
}

// per-bucket CSR build + inline norm; csr entry = src(16b) | f16norm << 16
__global__ __launch_bounds__(256) void k_bcsr(const uint2* __restrict__ dsw,
                                              const int* __restrict__ bstart_d,
                                              const float* __restrict__ dinv,
                                              int* __restrict__ row_start,
                                              unsigned* __restrict__ csr4) {
    __shared__ int ncnt[256];
    __shared__ int cur[256];
    __shared__ int sc[256];
    __shared__ float ldinv[256];
    int tid = threadIdx.x;
    int b = blockIdx.x;
    int node = (b << 8) + tid;
    ncnt[tid] = 0;
    ldinv[tid] = (node < N_NODES) ? dinv[node] : 0.f;
    __syncthreads();
    int e0 = bstart_d[b], e1 = bstart_d[b + 1];
    for (int i = e0 + tid; i < e1; i += 256)
        atomicAdd(&ncnt[(dsw[i].x >> 16) & 255], 1);  // LDS atomic
    __syncthreads();
    int v = ncnt[tid];
    sc[tid] = v;
    __syncthreads();
    for (int off = 1; off < 256; off <<= 1) {
        int t = (tid >= off) ? sc[tid - off] : 0;
        __syncthreads();
        sc[tid] += t;
        __syncthreads();
    }
    int excl = sc[tid] - v;
    cur[tid] = excl;
    if (node < N_NODES) row_start[node] = e0 + excl;
    __syncthreads();
    for (int i = e0 + tid; i < e1; i += 256) {
        uint2 sw = dsw[i];
        int srcn = sw.x & 0xFFFF;
        int ld = (sw.x >> 16) & 255;
        int p = e0 + atomicAdd(&cur[ld], 1);  // LDS atomic
        float nv = -dinv[srcn] * __uint_as_float(sw.y) * ldinv[ld];
        HBits hb; hb.h = __float2half(nv);
        csr4[p] = (unsigned)srcn | ((unsigned)hb.u << 16);
    }
}

// x fp32 -> X f16 (N x 128 contiguous)
__global__ void k_cvt_x(const float* __restrict__ x, __half* __restrict__ X, int n4) {
    int i = blockIdx.x * blockDim.x + threadIdx.x;
    if (i < n4) {
        float4 v = *(const float4*)&x[(size_t)i * 4];
        f16x4 o;
        o[0] = (_Float16)v.x; o[1] = (_Float16)v.y;
        o[2] = (_Float16)v.z; o[3] = (_Float16)v.w;
        *(f16x4*)&X[(size_t)i * 4] = o;
    }
}

// Build combined transposed weights for one layer:
// Wt[n*128 + k], n in [0,3C): slice0 = 2*W2, slice1 = W1, slice2 = W0 - W2.
__global__ void k_wt(const float* __restrict__ W, __half* __restrict__ Wt, int C) {
    int i = blockIdx.x * blockDim.x + threadIdx.x;
    if (i < 3 * C * 128) {
        int n = i >> 7, k = i & 127;
        int slice = n / C, c = n % C;
        float v;
        if (slice == 0)      v = 2.f * W[(size_t)(256 + k) * C + c];
        else if (slice == 1) v = W[(size_t)(128 + k) * C + c];
        else                 v = W[(size_t)k * C + c] - W[(size_t)(256 + k) * C + c];
        Wt[i] = __float2half(v);
    }
}

// ---------- SpMM: one wave per node, edge-pair dot2, direct csr loads -------
// R10 post-mortem: VALU is 75% busy but the MAC floor is only ~5us of ~40us -
// overhead dominates. R11: (a) per-lane direct csr loads with immediate
// offsets replace the csr-load + 8x ds_bpermute broadcast chain (zero addr
// VALU, no lgkm serialization); (b) pow2 gather strides (G padded to 512) ->
// sp<<10 addressing; (c) 16-edge mid-loop so the guarded tail covers <16
// edges instead of <32 (avg degree 32: half the edges were in the tail).
template <int ST_IN, int ST_ADD, int ST_OUT, int FW, int SIG, int F32>
__global__ __launch_bounds__(256) void k_spmm(const __half* __restrict__ Xin,
                                              const __half* __restrict__ Add,
                                              void* __restrict__ outp,
                                              const float* __restrict__ bias,
                                              const int* __restrict__ row_start,
                                              const unsigned* __restrict__ csr4) {
    constexpr int NL = FW / 8;      // feature lanes per edge (16 or 8)
    constexpr int EG = 64 / NL;     // edge groups (4 or 8)
    constexpr int KP2 = 16 / EG;    // pairs per lane in the 32-edge loop
    int node = blockIdx.x * 4 + (threadIdx.x >> 6);
    int lane = threadIdx.x & 63;
    int eg = lane / NL;
    int fs = lane % NL;
    int s = row_start[node];
    int e = row_start[node + 1];
    const unsigned* cb = csr4 + eg;
    const __half* Tbase = Xin + fs * 8;
    float acc[8];
    #pragma unroll
    for (int f = 0; f < 8; f++) acc[f] = 0.f;

    int j = s;
    for (; j + 32 <= e; j += 32) {           // 32-edge main loop
        unsigned ea[KP2], eb[KP2];
        #pragma unroll
        for (int k = 0; k < KP2; k++) {
            ea[k] = cb[j + 2 * EG * k];       // immediate offsets
            eb[k] = cb[j + 2 * EG * k + EG];
        }
        f16x8 r0[KP2], r1[KP2]; f16x2 nv2[KP2];
        #pragma unroll
        for (int k = 0; k < KP2; k++) {
            int sp0 = (int)(ea[k] & 0xFFFFu);
            int sp1 = (int)(eb[k] & 0xFFFFu);
            r0[k] = *(const f16x8*)&Tbase[(size_t)sp0 * ST_IN];
            r1[k] = *(const f16x8*)&Tbase[(size_t)sp1 * ST_IN];
            unsigned np = (ea[k] >> 16) | (eb[k] & 0xFFFF0000u);
            __builtin_memcpy(&nv2[k], &np, 4);
        }
        #pragma unroll
        for (int k = 0; k < KP2; k++)
            #pragma unroll
            for (int f = 0; f < 8; f++) {
                f16x2 h; h[0] = r0[k][f]; h[1] = r1[k][f];
                acc[f] = __builtin_amdgcn_fdot2(h, nv2[k], acc[f], false);
            }
    }
    if (j + 16 <= e) {                        // 16-edge mid loop
        unsigned ea[KP2 / 2], eb[KP2 / 2];
        #pragma unroll
        for (int k = 0; k < KP2 / 2; k++) {
            ea[k] = cb[j + 2 * EG * k];
            eb[k] = cb[j + 2 * EG * k + EG];
        }
        #pragma unroll
        for (int k = 0; k < KP2 / 2; k++) {
            int sp0 = (int)(ea[k] & 0xFFFFu);
            int sp1 = (int)(eb[k] & 0xFFFFu);
            f16x8 r0 = *(const f16x8*)&Tbase[(size_t)sp0 * ST_IN];
            f16x8 r1 = *(const f16x8*)&Tbase[(size_t)sp1 * ST_IN];
            unsigned np = (ea[k] >> 16) | (eb[k] & 0xFFFF0000u);
            f16x2 nv; __builtin_memcpy(&nv, &np, 4);
            #pragma unroll
            for (int f = 0; f < 8; f++) {
                f16x2 h; h[0] = r0[f]; h[1] = r1[f];
                acc[f] = __builtin_amdgcn_fdot2(h, nv, acc[f], false);
            }
        }
        j += 16;
    }
    if (j < e) {                              // guarded tail (<16 edges)
        #pragma unroll
        for (int k = 0; k < KP2 / 2; k++) {
            int i0 = j + 2 * EG * k + eg;
            int i1 = i0 + EG;
            unsigned va = csr4[min(i0, e - 1)];
            unsigned vb = csr4[min(i1, e - 1)];
            int sp0 = (int)(va & 0xFFFFu);
            int sp1 = (int)(vb & 0xFFFFu);
            unsigned np = (va >> 16) | (vb & 0xFFFF0000u);
            if (i0 >= e) np &= 0xFFFF0000u;
            if (i1 >= e) np &= 0x0000FFFFu;
            f16x2 nv; __builtin_memcpy(&nv, &np, 4);
            f16x8 r0 = *(const f16x8*)&Tbase[(size_t)sp0 * ST_IN];
            f16x8 r1 = *(const f16x8*)&Tbase[(size_t)sp1 * ST_IN];
            #pragma unroll
            for (int f = 0; f < 8; f++) {
                f16x2 h; h[0] = r0[f]; h[1] = r1[f];
                acc[f] = __builtin_amdgcn_fdot2(h, nv, acc[f], false);
            }
        }
    }
    // reduce edge-group partials
    #pragma unroll
    for (int f = 0; f < 8; f++)
        for (int m = NL; m < 64; m <<= 1)
            acc[f] += __shfl_xor(acc[f], m);
    if (eg == 0) {
        f16x8 av = *(const f16x8*)&Add[(size_t)node * ST_ADD + fs * 8];
        float v[8];
        #pragma unroll
        for (int f = 0; f < 8; f++) v[f] = acc[f] + (float)av[f];
        if (SIG) {
            #pragma unroll
            for (int f = 0; f < 8; f++) {
                v[f] += bias[fs * 8 + f];
                v[f] = 1.f / (1.f + expf(-v[f]));
            }
        }
        if (F32) {
            float* o = (float*)outp + (size_t)node * ST_OUT + fs * 8;
            float4 o0; o0.x = v[0]; o0.y = v[1]; o0.z = v[2]; o0.w = v[3];
            float4 o1; o1.x = v[4]; o1.y = v[5]; o1.z = v[6]; o1.w = v[7];
            *(float4*)&o[0] = o0;
            *(float4*)&o[4] = o1;
        } else {
            f16x8 o;
            #pragma unroll
            for (int f = 0; f < 8; f++) o[f] = (_Float16)v[f];
            *(f16x8*)((__half*)outp + (size_t)node * ST_OUT + fs * 8) = o;
        }
    }
}

// ---------- MFMA GEMM: G[M x 3C] = X[M x 128] @ Wt^T, merged columns --------
// One block = 64 rows x 3C cols (A staged once for all 3 col-chunks; 24 MFMA
// per stage vs 8 in the split version). G row stride STG (pow2-padded).
// mfma_f32_16x16x32_f16: A[m=lane&15][k=(lane>>4)*8+j]; C/D col=lane&15,row=(lane>>4)*4+r.
template <int CC, int STG>
__global__ __launch_bounds__(256) void k_gemm(const __half* __restrict__ A,
                                              const __half* __restrict__ Wt,
                                              __half* __restrict__ G, int M) {
    constexpr int N3 = 3 * CC;
    constexpr int NF = N3 / 16;
    __shared__ _Float16 As[64][40];
    __shared__ _Float16 Bs[N3][40];
    int tid = threadIdx.x;
    int wave = tid >> 6, lane = tid & 63;
    int lm = lane & 15, lq = lane >> 4;
    int m0 = blockIdx.x * 64;
    f32x4 acc[NF];
    for (int nf = 0; nf < NF; nf++) acc[nf] = (f32x4)0.0f;

    for (int k0 = 0; k0 < 128; k0 += 32) {
        {
            int r = tid >> 2, q = tid & 3;
            int row = m0 + r;
            if (row >= M) row = M - 1;
            *(f16x8*)&As[r][q * 8] = *(const f16x8*)&A[(size_t)row * 128 + k0 + q * 8];
        }
        for (int i = 0; i < N3 / 64; i++) {
            int idx = tid + i * 256;
            int n = idx >> 2, q = idx & 3;
            *(f16x8*)&Bs[n][q * 8] = *(const f16x8*)&Wt[(size_t)n * 128 + k0 + q * 8];
        }
        __syncthreads();
        f16x8 a = *(const f16x8*)&As[wave * 16 + lm][lq * 8];
        for (int nf = 0; nf < NF; nf++) {
            f16x8 b = *(const f16x8*)&Bs[nf * 16 + lm][lq * 8];
            acc[nf] = __builtin_amdgcn_mfma_f32_16x16x32_f16(a, b, acc[nf], 0, 0, 0);
        }
        __syncthreads();
    }
    for (int nf = 0; nf < NF; nf++) {
        for (int r = 0; r < 4; r++) {
            int grow = m0 + wave * 16 + lq * 4 + r;
            int col = nf * 16 + lm;
            if (grow < M)
                G[(size_t)grow * STG + col] = __float2half(acc[nf][r]);
        }
    }
}

extern "C" void kernel_launch(void* const* d_in, const int* in_sizes, int n_in,
                              void* d_out, int out_size, void* d_ws, size_t ws_size,
                              hipStream_t stream) {
    const float* x  = (const float*)d_in[0];
    const int*   ei = (const int*)d_in[1];
    const float* ew = (const float*)d_in[2];
    const float* W0 = (const float*)d_in[3];
    const float* b0 = (const float*)d_in[4];
    const float* W1 = (const float*)d_in[5];
    const float* b1 = (const float*)d_in[6];
    const float* W2 = (const float*)d_in[7];
    const float* b2 = (const float*)d_in[8];
    const int* src = ei;
    const int* dst = ei + N_EDGES;

    char* ws = (char*)d_ws;
    size_t off = 0;
    auto alloc = [&](size_t bytes) -> char* {
        size_t p = (off + 255) & ~(size_t)255;
        off = p + bytes;
        return ws + p;
    };
    __half*   X      = (__half*)alloc((size_t)N_NODES * 128 * 2);
    __half*   G      = (__half*)alloc((size_t)N_NODES * 512 * 2);   // [P|Q|S], stride 512 (pow2)
    __half*   TMP    = (__half*)alloc((size_t)N_NODES * 128 * 2);   // L*P + Q
    unsigned* csr4   = (unsigned*)alloc((size_t)N_EDGES * 4);       // src | f16norm<<16
    uint2*    dsw    = (uint2*)alloc((size_t)N_EDGES * 8);
    unsigned* ssw    = (unsigned*)alloc((size_t)N_EDGES * 4);       // sl | f16w<<16
    int*      bcnt_d = (int*)alloc((size_t)EBLK * 256 * 4);
    int*      bcnt_s = (int*)alloc((size_t)EBLK * 256 * 4);
    int*      btot   = (int*)alloc(512 * 4);
    int*      bstart_d = (int*)alloc(257 * 4);
    int*      bstart_s = (int*)alloc(257 * 4);
    int*      row_start= (int*)alloc((size_t)(N_NODES + 1) * 4);
    float*    dinv   = (float*)alloc((size_t)N_NODES * 4);
    __half*   Wt0    = (__half*)alloc((size_t)384 * 128 * 2);
    __half*   Wt1    = (__half*)alloc((size_t)384 * 128 * 2);
    __half*   Wt2    = (__half*)alloc((size_t)192 * 128 * 2);

    // dual bucket sort; zero device-scope atomics anywhere
    k_bcount<<<EBLK, 256, 0, stream>>>(src, dst, bcnt_d, bcnt_s);
    k_bscan1<<<512, 256, 0, stream>>>(bcnt_d, bcnt_s, btot);
    k_bscan2<<<1, 256, 0, stream>>>(btot, bstart_d, bstart_s, row_start);
    k_bscatter<<<EBLK, 256, 0, stream>>>(src, dst, ew, bcnt_d, bcnt_s,
                                         bstart_d, bstart_s, dsw, ssw);
    k_sdeg<<<NBUCK, 256, 0, stream>>>(ssw, bstart_s, dinv);
    k_bcsr<<<NBUCK, 256, 0, stream>>>(dsw, bstart_d, dinv, row_start, csr4);

    k_cvt_x<<<(N_NODES * 32 + 255) / 256, 256, 0, stream>>>(x, X, N_NODES * 32);
    k_wt<<<(3 * 128 * 128 + 255) / 256, 256, 0, stream>>>(W0, Wt0, 128);
    k_wt<<<(3 * 128 * 128 + 255) / 256, 256, 0, stream>>>(W1, Wt1, 128);
    k_wt<<<(3 * 64 * 128 + 255) / 256, 256, 0, stream>>>(W2, Wt2, 64);

    int gb = (N_NODES + 63) / 64;   // 782
    int sb = N_NODES / 4;           // 12500
    // layer 0: G = X @ [Wc|Wb|Wa] (P@0, Q@128, S@256; stride 512)
    // TMP = L*P + Q;  X = sigmoid(L*TMP + S + b0)
    k_gemm<128, 512><<<gb, 256, 0, stream>>>(X, Wt0, G, N_NODES);
    k_spmm<512, 512, 128, 128, 0, 0><<<sb, 256, 0, stream>>>(G, G + 128, TMP,
                                                             nullptr, row_start, csr4);
    k_spmm<128, 512, 128, 128, 1, 0><<<sb, 256, 0, stream>>>(TMP, G + 256, X,
                                                             b0, row_start, csr4);
    // layer 1
    k_gemm<128, 512><<<gb, 256, 0, stream>>>(X, Wt1, G, N_NODES);
    k_spmm<512, 512, 128, 128, 0, 0><<<sb, 256, 0, stream>>>(G, G + 128, TMP,
                                                             nullptr, row_start, csr4);
    k_spmm<128, 512, 128, 128, 1, 0><<<sb, 256, 0, stream>>>(TMP, G + 256, X,
                                                             b1, row_start, csr4);
    // layer 2 (C=64): stride 256 (P@0, Q@64, S@128)
    k_gemm<64, 256><<<gb, 256, 0, stream>>>(X, Wt2, G, N_NODES);
    k_spmm<256, 256, 64, 64, 0, 0><<<sb, 256, 0, stream>>>(G, G + 64, TMP,
                                                           nullptr, row_start, csr4);
    k_spmm<64, 256, 64, 64, 1, 1><<<sb, 256, 0, stream>>>(TMP, G + 128, d_out,
                                                          b2, row_start, csr4);
}

// Round 13
// 487.243 us; speedup vs baseline: 2.9845x; 1.0151x over previous
//
#include <hip/hip_runtime.h>
#include <hip/hip_fp16.h>
#include <math.h>

#define N_NODES 50000
#define N_EDGES 1600000
#define NBUCK 196          // node >> 8 buckets (50000/256)
#define EBLK 400           // edge blocks for sort
#define CHUNK 4000         // edges per block (EBLK*CHUNK == N_EDGES)
#define CSR_CAP (N_EDGES + 2048 * NBUCK + 4096)

typedef _Float16 f16x8 __attribute__((ext_vector_type(8)));
typedef _Float16 f16x4 __attribute__((ext_vector_type(4)));
typedef _Float16 f16x2 __attribute__((ext_vector_type(2)));
typedef float f32x4 __attribute__((ext_vector_type(4)));

union HBits { __half h; unsigned short u; };

// ---------- dual bucket sort (dst-keyed for CSR, src-keyed for deg) ----------
__global__ __launch_bounds__(256) void k_bcount(const int* __restrict__ src,
                                                const int* __restrict__ dst,
                                                int* __restrict__ bcnt_d,
                                                int* __restrict__ bcnt_s) {
    __shared__ int lcd[256];
    __shared__ int lcs[256];
    int tid = threadIdx.x;
    lcd[tid] = 0; lcs[tid] = 0;
    __syncthreads();
    int base = blockIdx.x * CHUNK;
    for (int i = tid; i < CHUNK; i += 256) {
        atomicAdd(&lcd[dst[base + i] >> 8], 1);
        atomicAdd(&lcs[src[base + i] >> 8], 1);
    }
    __syncthreads();
    bcnt_d[blockIdx.x * 256 + tid] = lcd[tid];
    bcnt_s[blockIdx.x * 256 + tid] = lcs[tid];
}

// per-bucket scan over edge-blocks (parallel)
__global__ __launch_bounds__(256) void k_bscan1(int* __restrict__ bcnt_d,
                                                int* __restrict__ bcnt_s,
                                                int* __restrict__ btot) {
    int b = blockIdx.x & 255;
    int* bcnt = (blockIdx.x >> 8) ? bcnt_s : bcnt_d;
    int tid = threadIdx.x;
    int k0 = 2 * tid;
    int v0 = (k0 < EBLK) ? bcnt[k0 * 256 + b] : 0;
    int v1 = (k0 + 1 < EBLK) ? bcnt[(k0 + 1) * 256 + b] : 0;
    int pair = v0 + v1;
    __shared__ int s[256];
    s[tid] = pair;
    __syncthreads();
    for (int off = 1; off < 256; off <<= 1) {
        int t = (tid >= off) ? s[tid - off] : 0;
        __syncthreads();
        s[tid] += t;
        __syncthreads();
    }
    int excl = s[tid] - pair;
    if (k0 < EBLK)     bcnt[k0 * 256 + b] = excl;
    if (k0 + 1 < EBLK) bcnt[(k0 + 1) * 256 + b] = excl + v0;
    if (tid == 255) btot[(blockIdx.x >> 8) * 256 + b] = s[255];
}

__global__ __launch_bounds__(256) void k_bscan2(const int* __restrict__ btot,
                                                int* __restrict__ bstart_d,
                                                int* __restrict__ bstart_s) {
    __shared__ int s[256];
    int b = threadIdx.x;
    int v = btot[b];
    s[b] = v;
    __syncthreads();
    for (int off = 1; off < 256; off <<= 1) {
        int t = (b >= off) ? s[b - off] : 0;
        __syncthreads();
        s[b] += t;
        __syncthreads();
    }
    bstart_d[b] = s[b] - v;
    if (b == 0) bstart_d[256] = N_EDGES;
    __syncthreads();
    int v2 = btot[256 + b];
    s[b] = v2;
    __syncthreads();
    for (int off = 1; off < 256; off <<= 1) {
        int t = (b >= off) ? s[b - off] : 0;
        __syncthreads();
        s[b] += t;
        __syncthreads();
    }
    bstart_s[b] = s[b] - v2;
    if (b == 0) bstart_s[256] = N_EDGES;
}

// scatter packed records into both sorted orders (LDS cursors only)
// dsw: {src | dst_local<<16, f32 w}; ssw: src_local | f16w<<16 (4 B)
__global__ __launch_bounds__(256) void k_bscatter(const int* __restrict__ src,
                                                  const int* __restrict__ dst,
                                                  const float* __restrict__ w,
                                                  const int* __restrict__ bcnt_d,
                                                  const int* __restrict__ bcnt_s,
                                                  const int* __restrict__ bstart_d,
                                                  const int* __restrict__ bstart_s,
                                                  uint2* __restrict__ dsw,
                                                  unsigned* __restrict__ ssw) {
    __shared__ int curd[256];
    __shared__ int curs[256];
    int tid = threadIdx.x;
    curd[tid] = bcnt_d[blockIdx.x * 256 + tid] + bstart_d[tid];
    curs[tid] = bcnt_s[blockIdx.x * 256 + tid] + bstart_s[tid];
    __syncthreads();
    int base = blockIdx.x * CHUNK;
    for (int i = tid; i < CHUNK; i += 256) {
        int d = dst[base + i];
        int ss = src[base + i];
        float wi = w[base + i];
        int p = atomicAdd(&curd[d >> 8], 1);   // LDS atomic
        uint2 r; r.x = (unsigned)ss | ((unsigned)(d & 255) << 16);
        r.y = __float_as_uint(wi);
        dsw[p] = r;
        int q = atomicAdd(&curs[ss >> 8], 1);  // LDS atomic
        HBits hw; hw.h = __float2half(wi);
        ssw[q] = (unsigned)(ss & 255) | ((unsigned)hw.u << 16);
    }
}

// deg per src-bucket -> dinv (f16 w partials: ~0.05% deg error, negligible)
__global__ __launch_bounds__(256) void k_sdeg(const unsigned* __restrict__ ssw,
                                              const int* __restrict__ bstart_s,
                                              float* __restrict__ dinv) {
    __shared__ float h[256];
    int tid = threadIdx.x;
    int b = blockIdx.x;
    h[tid] = 0.f;
    __syncthreads();
    int e0 = bstart_s[b], e1 = bstart_s[b + 1];
    for (int i = e0 + tid; i < e1; i += 256) {
        unsigned r = ssw[i];
        HBits hb; hb.u = (unsigned short)(r >> 16);
        atomicAdd(&h[r & 255], __half2float(hb.h));  // LDS atomic
    }
    __syncthreads();
    int node = (b << 8) + tid;
    if (node < N_NODES) {
        float d = h[tid];
        dinv[node] = d > 0.f ? rsqrtf(fmaxf(d, 1e-30f)) : 0.f;
    }
}

// per-bucket CSR build + inline norm. Rows PADDED to multiples of 8 with
// zero entries (src=0, norm=0) so every row start is 8-aligned and spmm needs
// no guarded tail. csr entry = src(16b) | f16norm<<16. ri[node]={start,pcnt}.
// Bucket b's padded region starts at ((bstart_d[b]+7)&~7) + 2048*b
// (max pad 7*256=1792 < 2048-7, regions provably disjoint).
__global__ __launch_bounds__(256) void k_bcsr(const uint2* __restrict__ dsw,
                                              const int* __restrict__ bstart_d,
                                              const float* __restrict__ dinv,
                                              uint2* __restrict__ ri,
                                              unsigned* __restrict__ csr4) {
    __shared__ int ncnt[256];
    __shared__ int cur[256];
    __shared__ int sc[256];
    __shared__ float ldinv[256];
    int tid = threadIdx.x;
    int b = blockIdx.x;
    int node = (b << 8) + tid;
    ncnt[tid] = 0;
    ldinv[tid] = (node < N_NODES) ? dinv[node] : 0.f;
    __syncthreads();
    int e0 = bstart_d[b], e1 = bstart_d[b + 1];
    for (int i = e0 + tid; i < e1; i += 256)
        atomicAdd(&ncnt[(dsw[i].x >> 16) & 255], 1);  // LDS atomic
    __syncthreads();
    int v = ncnt[tid];
    int pc = (v + 7) & ~7;                            // padded count
    sc[tid] = pc;
    __syncthreads();
    for (int off = 1; off < 256; off <<= 1) {
        int t = (tid >= off) ? sc[tid - off] : 0;
        __syncthreads();
        sc[tid] += t;
        __syncthreads();
    }
    int excl = sc[tid] - pc;
    cur[tid] = excl;
    int pbase = ((e0 + 7) & ~7) + 2048 * b;
    if (node < N_NODES) {
        uint2 r; r.x = (unsigned)(pbase + excl); r.y = (unsigned)pc;
        ri[node] = r;
    }
    __syncthreads();
    for (int i = e0 + tid; i < e1; i += 256) {
        uint2 sw = dsw[i];
        int srcn = sw.x & 0xFFFF;
        int ld = (sw.x >> 16) & 255;
        int p = pbase + atomicAdd(&cur[ld], 1);  // LDS atomic
        float nv = -dinv[srcn] * __uint_as_float(sw.y) * ldinv[ld];
        HBits hb; hb.h = __float2half(nv);
        csr4[p] = (unsigned)srcn | ((unsigned)hb.u << 16);
    }
    __syncthreads();
    // zero-norm fillers
    int st = pbase + excl;
    for (int i = v; i < pc; i++) csr4[st + i] = 0u;
}

// merged prep: x fp32 -> X f16 (blocks 0..6249), Wt builds (rest).
// Wt[n*128 + k], n in [0,3C): slice0 = 2*W2, slice1 = W1, slice2 = W0 - W2.
__device__ inline void wt_one(const float* __restrict__ W, __half* __restrict__ Wt,
                              int C, int i) {
    int n = i >> 7, k = i & 127;
    int slice = n / C, c = n % C;
    float v;
    if (slice == 0)      v = 2.f * W[(size_t)(256 + k) * C + c];
    else if (slice == 1) v = W[(size_t)(128 + k) * C + c];
    else                 v = W[(size_t)k * C + c] - W[(size_t)(256 + k) * C + c];
    Wt[i] = __float2half(v);
}

__global__ __launch_bounds__(256) void k_prep(const float* __restrict__ x,
                                              __half* __restrict__ X,
                                              const float* __restrict__ W0,
                                              const float* __restrict__ W1,
                                              const float* __restrict__ W2,
                                              __half* __restrict__ Wt0,
                                              __half* __restrict__ Wt1,
                                              __half* __restrict__ Wt2) {
    int bid = blockIdx.x, tid = threadIdx.x;
    if (bid < 6250) {
        int i = bid * 256 + tid;          // float4 index, 1.6M total
        float4 v = *(const float4*)&x[(size_t)i * 4];
        f16x4 o;
        o[0] = (_Float16)v.x; o[1] = (_Float16)v.y;
        o[2] = (_Float16)v.z; o[3] = (_Float16)v.w;
        *(f16x4*)&X[(size_t)i * 4] = o;
    } else if (bid < 6250 + 192) {
        wt_one(W0, Wt0, 128, (bid - 6250) * 256 + tid);
    } else if (bid < 6250 + 384) {
        wt_one(W1, Wt1, 128, (bid - 6250 - 192) * 256 + tid);
    } else {
        wt_one(W2, Wt2, 64, (bid - 6250 - 384) * 256 + tid);
    }
}

// ---------- SpMM: one wave per node, pair-dot2, wide aligned csr loads ------
// R11 post-mortem: VMEM instr count per iter (16: 8 csr dwords + 8 gathers)
// is the bound, not VALU or fetch. R12: pair-adjacent edge assignment ->
// dwordx4 csr loads (2/iter), rows padded to x8 (aligned, NO guarded tail).
// Gather batching unchanged: 8 (FW=128) / 4 (FW=64) in flight.
__device__ inline void mac_pair(const __half* __restrict__ Tbase, unsigned ea,
                                unsigned eb, int stin, float acc[8]) {
    f16x8 r0 = *(const f16x8*)&Tbase[(size_t)(ea & 0xFFFFu) * stin];
    f16x8 r1 = *(const f16x8*)&Tbase[(size_t)(eb & 0xFFFFu) * stin];
    unsigned np = (ea >> 16) | (eb & 0xFFFF0000u);
    f16x2 nv; __builtin_memcpy(&nv, &np, 4);
    #pragma unroll
    for (int f = 0; f < 8; f++) {
        f16x2 h; h[0] = r0[f]; h[1] = r1[f];
        acc[f] = __builtin_amdgcn_fdot2(h, nv, acc[f], false);
    }
}

template <int ST_IN, int ST_ADD, int ST_OUT, int FW, int SIG, int F32>
__global__ __launch_bounds__(256) void k_spmm(const __half* __restrict__ Xin,
                                              const __half* __restrict__ Add,
                                              void* __restrict__ outp,
                                              const float* __restrict__ bias,
                                              const uint2* __restrict__ ri,
                                              const unsigned* __restrict__ csr4) {
    constexpr int NL = FW / 8;      // feature lanes per edge (16 or 8)
    constexpr int EG = 64 / NL;     // edge groups (4 or 8)
    int node = blockIdx.x * 4 + (threadIdx.x >> 6);
    int lane = threadIdx.x & 63;
    int eg = lane / NL;
    int fs = lane % NL;
    uint2 rv = ri[node];
    int s = (int)rv.x;
    int e = s + (int)rv.y;                  // count is multiple of 8
    const __half* Tbase = Xin + fs * 8;
    float acc[8];
    #pragma unroll
    for (int f = 0; f < 8; f++) acc[f] = 0.f;

    int j = s;
    if (EG == 4) {                          // FW=128: group owns 8 edges/iter
        for (; j + 32 <= e; j += 32) {
            uint4 c0 = *(const uint4*)&csr4[j + 4 * eg];
            uint4 c1 = *(const uint4*)&csr4[j + 16 + 4 * eg];
            unsigned ea[4] = {c0.x, c0.z, c1.x, c1.z};
            unsigned eb[4] = {c0.y, c0.w, c1.y, c1.w};
            f16x8 r0[4], r1[4];
            #pragma unroll
            for (int k = 0; k < 4; k++) {
                r0[k] = *(const f16x8*)&Tbase[(size_t)(ea[k] & 0xFFFFu) * ST_IN];
                r1[k] = *(const f16x8*)&Tbase[(size_t)(eb[k] & 0xFFFFu) * ST_IN];
            }
            #pragma unroll
            for (int k = 0; k < 4; k++) {
                unsigned np = (ea[k] >> 16) | (eb[k] & 0xFFFF0000u);
                f16x2 nv; __builtin_memcpy(&nv, &np, 4);
                #pragma unroll
                for (int f = 0; f < 8; f++) {
                    f16x2 h; h[0] = r0[k][f]; h[1] = r1[k][f];
                    acc[f] = __builtin_amdgcn_fdot2(h, nv, acc[f], false);
                }
            }
        }
        if (j + 16 <= e) {
            uint4 c0 = *(const uint4*)&csr4[j + 4 * eg];
            mac_pair(Tbase, c0.x, c0.y, ST_IN, acc);
            mac_pair(Tbase, c0.z, c0.w, ST_IN, acc);
            j += 16;
        }
        if (j + 8 <= e) {
            uint2 c = *(const uint2*)&csr4[j + 2 * eg];
            mac_pair(Tbase, c.x, c.y, ST_IN, acc);
        }
    } else {                                // FW=64, EG=8: group owns 4/iter
        for (; j + 32 <= e; j += 32) {
            uint4 c0 = *(const uint4*)&csr4[j + 4 * eg];
            unsigned ea[2] = {c0.x, c0.z};
            unsigned eb[2] = {c0.y, c0.w};
            f16x8 r0[2], r1[2];
            #pragma unroll
            for (int k = 0; k < 2; k++) {
                r0[k] = *(const f16x8*)&Tbase[(size_t)(ea[k] & 0xFFFFu) * ST_IN];
                r1[k] = *(const f16x8*)&Tbase[(size_t)(eb[k] & 0xFFFFu) * ST_IN];
            }
            #pragma unroll
            for (int k = 0; k < 2; k++) {
                unsigned np = (ea[k] >> 16) | (eb[k] & 0xFFFF0000u);
                f16x2 nv; __builtin_memcpy(&nv, &np, 4);
                #pragma unroll
                for (int f = 0; f < 8; f++) {
                    f16x2 h; h[0] = r0[k][f]; h[1] = r1[k][f];
                    acc[f] = __builtin_amdgcn_fdot2(h, nv, acc[f], false);
                }
            }
        }
        if (j + 16 <= e) {
            uint2 c = *(const uint2*)&csr4[j + 2 * eg];
            mac_pair(Tbase, c.x, c.y, ST_IN, acc);
            j += 16;
        }
        if (j + 8 <= e) {
            uint2 c = *(const uint2*)&csr4[j + 2 * (eg & 3)];
            unsigned ea = c.x, eb = c.y;
            if (eg >= 4) { ea &= 0xFFFFu; eb &= 0xFFFFu; }  // zero norms (dup groups)
            mac_pair(Tbase, ea, eb, ST_IN, acc);
        }
    }
    // reduce edge-group partials
    #pragma unroll
    for (int f = 0; f < 8; f++)
        for (int m = NL; m < 64; m <<= 1)
            acc[f] += __shfl_xor(acc[f], m);
    if (eg == 0) {
        f16x8 av = *(const f16x8*)&Add[(size_t)node * ST_ADD + fs * 8];
        float v[8];
        #pragma unroll
        for (int f = 0; f < 8; f++) v[f] = acc[f] + (float)av[f];
        if (SIG) {
            #pragma unroll
            for (int f = 0; f < 8; f++) {
                v[f] += bias[fs * 8 + f];
                v[f] = 1.f / (1.f + expf(-v[f]));
            }
        }
        if (F32) {
            float* o = (float*)outp + (size_t)node * ST_OUT + fs * 8;
            float4 o0; o0.x = v[0]; o0.y = v[1]; o0.z = v[2]; o0.w = v[3];
            float4 o1; o1.x = v[4]; o1.y = v[5]; o1.z = v[6]; o1.w = v[7];
            *(float4*)&o[0] = o0;
            *(float4*)&o[4] = o1;
        } else {
            f16x8 o;
            #pragma unroll
            for (int f = 0; f < 8; f++) o[f] = (_Float16)v[f];
            *(f16x8*)((__half*)outp + (size_t)node * ST_OUT + fs * 8) = o;
        }
    }
}

// ---------- MFMA GEMM: G[M x 3C] = X[M x 128] @ Wt^T, merged columns --------
// mfma_f32_16x16x32_f16: A[m=lane&15][k=(lane>>4)*8+j]; C/D col=lane&15,row=(lane>>4)*4+r.
template <int CC, int STG>
__global__ __launch_bounds__(256) void k_gemm(const __half* __restrict__ A,
                                              const __half* __restrict__ Wt,
                                              __half* __restrict__ G, int M) {
    constexpr int N3 = 3 * CC;
    constexpr int NF = N3 / 16;
    __shared__ _Float16 As[64][40];
    __shared__ _Float16 Bs[N3][40];
    int tid = threadIdx.x;
    int wave = tid >> 6, lane = tid & 63;
    int lm = lane & 15, lq = lane >> 4;
    int m0 = blockIdx.x * 64;
    f32x4 acc[NF];
    for (int nf = 0; nf < NF; nf++) acc[nf] = (f32x4)0.0f;

    for (int k0 = 0; k0 < 128; k0 += 32) {
        {
            int r = tid >> 2, q = tid & 3;
            int row = m0 + r;
            if (row >= M) row = M - 1;
            *(f16x8*)&As[r][q * 8] = *(const f16x8*)&A[(size_t)row * 128 + k0 + q * 8];
        }
        for (int i = 0; i < N3 / 64; i++) {
            int idx = tid + i * 256;
            int n = idx >> 2, q = idx & 3;
            *(f16x8*)&Bs[n][q * 8] = *(const f16x8*)&Wt[(size_t)n * 128 + k0 + q * 8];
        }
        __syncthreads();
        f16x8 a = *(const f16x8*)&As[wave * 16 + lm][lq * 8];
        for (int nf = 0; nf < NF; nf++) {
            f16x8 b = *(const f16x8*)&Bs[nf * 16 + lm][lq * 8];
            acc[nf] = __builtin_amdgcn_mfma_f32_16x16x32_f16(a, b, acc[nf], 0, 0, 0);
        }
        __syncthreads();
    }
    for (int nf = 0; nf < NF; nf++) {
        for (int r = 0; r < 4; r++) {
            int grow = m0 + wave * 16 + lq * 4 + r;
            int col = nf * 16 + lm;
            if (grow < M)
                G[(size_t)grow * STG + col] = __float2half(acc[nf][r]);
        }
    }
}

extern "C" void kernel_launch(void* const* d_in, const int* in_sizes, int n_in,
                              void* d_out, int out_size, void* d_ws, size_t ws_size,
                              hipStream_t stream) {
    const float* x  = (const float*)d_in[0];
    const int*   ei = (const int*)d_in[1];
    const float* ew = (const float*)d_in[2];
    const float* W0 = (const float*)d_in[3];
    const float* b0 = (const float*)d_in[4];
    const float* W1 = (const float*)d_in[5];
    const float* b1 = (const float*)d_in[6];
    const float* W2 = (const float*)d_in[7];
    const float* b2 = (const float*)d_in[8];
    const int* src = ei;
    const int* dst = ei + N_EDGES;

    char* ws = (char*)d_ws;
    size_t off = 0;
    auto alloc = [&](size_t bytes) -> char* {
        size_t p = (off + 255) & ~(size_t)255;
        off = p + bytes;
        return ws + p;
    };
    __half*   X      = (__half*)alloc((size_t)N_NODES * 128 * 2);
    __half*   G      = (__half*)alloc((size_t)N_NODES * 512 * 2);   // [P|Q|S], stride 512
    __half*   TMP    = (__half*)alloc((size_t)N_NODES * 128 * 2);   // L*P + Q
    unsigned* csr4   = (unsigned*)alloc((size_t)CSR_CAP * 4);       // padded CSR
    uint2*    ri     = (uint2*)alloc((size_t)N_NODES * 8);          // (start, pcount)
    uint2*    dsw    = (uint2*)alloc((size_t)N_EDGES * 8);
    unsigned* ssw    = (unsigned*)alloc((size_t)N_EDGES * 4);       // sl | f16w<<16
    int*      bcnt_d = (int*)alloc((size_t)EBLK * 256 * 4);
    int*      bcnt_s = (int*)alloc((size_t)EBLK * 256 * 4);
    int*      btot   = (int*)alloc(512 * 4);
    int*      bstart_d = (int*)alloc(257 * 4);
    int*      bstart_s = (int*)alloc(257 * 4);
    float*    dinv   = (float*)alloc((size_t)N_NODES * 4);
    __half*   Wt0    = (__half*)alloc((size_t)384 * 128 * 2);
    __half*   Wt1    = (__half*)alloc((size_t)384 * 128 * 2);
    __half*   Wt2    = (__half*)alloc((size_t)192 * 128 * 2);

    // dual bucket sort; zero device-scope atomics anywhere
    k_bcount<<<EBLK, 256, 0, stream>>>(src, dst, bcnt_d, bcnt_s);
    k_bscan1<<<512, 256, 0, stream>>>(bcnt_d, bcnt_s, btot);
    k_bscan2<<<1, 256, 0, stream>>>(btot, bstart_d, bstart_s);
    k_bscatter<<<EBLK, 256, 0, stream>>>(src, dst, ew, bcnt_d, bcnt_s,
                                         bstart_d, bstart_s, dsw, ssw);
    k_sdeg<<<NBUCK, 256, 0, stream>>>(ssw, bstart_s, dinv);
    k_bcsr<<<NBUCK, 256, 0, stream>>>(dsw, bstart_d, dinv, ri, csr4);

    k_prep<<<6250 + 192 + 192 + 96, 256, 0, stream>>>(x, X, W0, W1, W2, Wt0, Wt1, Wt2);

    int gb = (N_NODES + 63) / 64;   // 782
    int sb = N_NODES / 4;           // 12500
    // layer 0: G = X @ [Wc|Wb|Wa] (P@0, Q@128, S@256; stride 512)
    // TMP = L*P + Q;  X = sigmoid(L*TMP + S + b0)
    k_gemm<128, 512><<<gb, 256, 0, stream>>>(X, Wt0, G, N_NODES);
    k_spmm<512, 512, 128, 128, 0, 0><<<sb, 256, 0, stream>>>(G, G + 128, TMP,
                                                             nullptr, ri, csr4);
    k_spmm<128, 512, 128, 128, 1, 0><<<sb, 256, 0, stream>>>(TMP, G + 256, X,
                                                             b0, ri, csr4);
    // layer 1
    k_gemm<128, 512><<<gb, 256, 0, stream>>>(X, Wt1, G, N_NODES);
    k_spmm<512, 512, 128, 128, 0, 0><<<sb, 256, 0, stream>>>(G, G + 128, TMP,
                                                             nullptr, ri, csr4);
    k_spmm<128, 512, 128, 128, 1, 0><<<sb, 256, 0, stream>>>(TMP, G + 256, X,
                                                             b1, ri, csr4);
    // layer 2 (C=64): stride 256 (P@0, Q@64, S@128)
    k_gemm<64, 256><<<gb, 256, 0, stream>>>(X, Wt2, G, N_NODES);
    k_spmm<256, 256, 64, 64, 0, 0><<<sb, 256, 0, stream>>>(G, G + 64, TMP,
                                                           nullptr, ri, csr4);
    k_spmm<64, 256, 64, 64, 1, 1><<<sb, 256, 0, stream>>>(TMP, G + 128, d_out,
                                                          b2, ri, csr4);
}